// Round 9
// baseline (376.969 us; speedup 1.0000x reference)
//
#include <hip/hip_runtime.h>

#define NNODES 50000
#define NPAD   50048   // 391 * 128; padded row count so 128-tile GEMM staging never faults
#define NEDGES 800000
#define NGRAPH 512
#define DCAP 64   // padded edge slots per node; Poisson(16) max ~37, P(>=64) ~ 1e-23

typedef short bf16x8 __attribute__((ext_vector_type(8)));
typedef unsigned short u16x8 __attribute__((ext_vector_type(8)));
typedef float f32x4 __attribute__((ext_vector_type(4)));
typedef unsigned long long u64;

// async global->LDS, 16B per lane (dest = wave-uniform base + lane*16, linear layout)
#define GLOAD16(g, l)                                                                 \
    __builtin_amdgcn_global_load_lds((const __attribute__((address_space(1))) unsigned*)(g), \
                                     (__attribute__((address_space(3))) unsigned*)(l), 16, 0, 0)

// ---------- bf16 <-> fp32 helpers ----------
static __device__ __forceinline__ float b2f(unsigned short u) {
    return __uint_as_float(((unsigned)u) << 16);
}
static __device__ __forceinline__ unsigned short f2b(float f) {
    unsigned u = __float_as_uint(f);
    unsigned r = (u + 0x7fffu + ((u >> 16) & 1u)) >> 16;  // round-nearest-even
    return (unsigned short)r;
}

// accumulate 8 bf16 (packed in uint4) * c into acc[8]
static __device__ __forceinline__ void accum8(float (&acc)[8], float c, uint4 v) {
    unsigned w[4] = {v.x, v.y, v.z, v.w};
    #pragma unroll
    for (int i = 0; i < 4; ++i) {
        acc[2 * i]     += c * __uint_as_float(w[i] << 16);
        acc[2 * i + 1] += c * __uint_as_float(w[i] & 0xffff0000u);
    }
}

// ---------- fused graph-build: weight transposes (blocks 0..203) + edge placement ----------
// deg_cnt: ONE 64B LINE PER NODE (index node<<3) -> no false sharing between nodes'
// atomics; only true per-node contention (~16-way) remains. Init via hipMemsetAsync(0);
// the self-loop's +1.0 weight is folded into the dinv formula instead.
// Edge blocks: 1 edge/thread (3125 blocks) for max wave occupancy; transpose blocks'
// regular memory work overlaps the atomic latency inside the same dispatch.
__global__ __launch_bounds__(256) void k_graph(const float* __restrict__ W1, const float* __restrict__ W2,
                                               const float* __restrict__ W3, const float* __restrict__ Wf1,
                                               const float* __restrict__ Wf2,
                                               unsigned short* __restrict__ T1, unsigned short* __restrict__ T2,
                                               unsigned short* __restrict__ T3, unsigned short* __restrict__ Tf1,
                                               unsigned short* __restrict__ Tf2,
                                               const int* __restrict__ ei_s, const int* __restrict__ ei_d,
                                               const float* __restrict__ ew,
                                               u64* deg_cnt, unsigned* __restrict__ edges) {
    const int b = blockIdx.x;
    if (b < 204) {
        // W[K][N] fp32 -> WT[N][K] bf16, 64x64 LDS tile, both global sides coalesced
        const float* W; unsigned short* T; int K, N, t0;
        if (b < 4)        { W = W1;  T = T1;  K = 128;  N = 128;  t0 = 0;   }
        else if (b < 12)  { W = W2;  T = T2;  K = 128;  N = 256;  t0 = 4;   }
        else if (b < 44)  { W = W3;  T = T3;  K = 256;  N = 512;  t0 = 12;  }
        else if (b < 172) { W = Wf1; T = Tf1; K = 512;  N = 1024; t0 = 44;  }
        else              { W = Wf2; T = Tf2; K = 1024; N = 128;  t0 = 172; }
        const int tile = b - t0;
        const int ntn = N >> 6;
        const int k0 = (tile / ntn) * 64, n0 = (tile % ntn) * 64;
        __shared__ float sm[64][65];
        const int t = threadIdx.x;
        const int rr = t >> 6, cc = t & 63;
        #pragma unroll
        for (int r = 0; r < 16; ++r) {
            int kl = r * 4 + rr;
            sm[kl][cc] = W[(size_t)(k0 + kl) * N + n0 + cc];
        }
        __syncthreads();
        #pragma unroll
        for (int r = 0; r < 16; ++r) {
            int nl = r * 4 + rr;
            T[(size_t)(n0 + nl) * K + k0 + cc] = f2b(sm[cc][nl]);
        }
        return;
    }
    // edge placement: u64 atomic returns old count = this edge's slot
    const int e = (b - 204) * 256 + threadIdx.x;
    if (e >= NEDGES) return;
    const int s = ei_s[e];
    const int d = ei_d[e];
    const float w = ew[e];
    const unsigned fixed = __float2uint_rn(w * 16777216.0f);  // 8.24 fixed; ew in [0,1)
    u64 old = atomicAdd(&deg_cnt[(size_t)d << 3], ((u64)1 << 32) | fixed);
    int slot = (int)(old >> 32);
    if (slot > DCAP - 1) slot = DCAP - 1;  // never fires (safety)
    edges[((unsigned)d << 6) | slot] = ((unsigned)f2b(w) << 16) | (unsigned)s;
}

// fp32 -> bf16 with per-row dinv scale (deg = edge-weight sum + 1.0 self-loop)
__global__ void k_cvt_prep(const float* __restrict__ X, const u64* __restrict__ deg_cnt,
                           float* __restrict__ dinv, unsigned short* __restrict__ Y, int n4) {
    int i = blockIdx.x * 256 + threadIdx.x;
    if (i < n4) {
        int row = i >> 5;   // 32 float4 per 128-wide row
        float d = rsqrtf((float)(unsigned)(deg_cnt[(size_t)row << 3] & 0xffffffffull) * 5.9604645e-8f + 1.0f);
        if ((i & 31) == 0) dinv[row] = d;
        float4 v = ((const float4*)X)[i];
        uint2 o;
        o.x = (unsigned)f2b(v.x * d) | ((unsigned)f2b(v.y * d) << 16);
        o.y = (unsigned)f2b(v.z * d) | ((unsigned)f2b(v.w * d) << 16);
        ((uint2*)Y)[i] = o;
    }
}

// ---------- aggregation: Z[d,:] = dinv[d] * (X'[d,:] + sum_e ew_e * X'[src_e,:]) ----------
// wave-per-(node, feature-slice). SLICES=1: round-2 verified form. SLICES=2 (F=256):
// slice = bid&1 -> under round-robin block->XCD dispatch, slice parity == XCD parity,
// so each XCD's L2 works on a 12.8MB half-table (r8: FETCH 187->162MB, 58.4->56.6us).
// 16B dwordx4 gathers, rotating 2-deep pipeline, weight-0 masked tail,
// cross-group shfl reduce, 16B stores by group 0.
template <int F, int SLICES>
__global__ __launch_bounds__(256) void k_aggregate(const unsigned short* __restrict__ X,
                                                   const u64* __restrict__ deg_cnt,
                                                   const unsigned* __restrict__ edges,
                                                   const float* __restrict__ dinv,
                                                   unsigned short* __restrict__ Z) {
    constexpr int FS = F / SLICES;     // features handled per block
    constexpr int LPR = FS / 8;        // lanes per source row-slice (16 or 32)
    constexpr int GRP = 64 / LPR;      // edges per step (4 or 2)
    constexpr int STEP = GRP * 2;      // edges per pair-iteration (8 or 4)
    const int bid = blockIdx.x;
    const int slice = (SLICES == 1) ? 0 : (bid & (SLICES - 1));
    const int chunk = (SLICES == 1) ? bid : (bid / SLICES);
    const int wave = threadIdx.x >> 6, lane = threadIdx.x & 63;
    const int node = chunk * 4 + wave;
    if (node >= NNODES) return;
    const int sub = lane & (LPR - 1);
    const int grp = lane / LPR;
    const int fo = slice * FS + sub * 8;
    const unsigned short* Xf = X + fo;
    const float di = dinv[node];
    const int cnt = (int)(deg_cnt[(size_t)node << 3] >> 32);
    const unsigned* erow = edges + ((unsigned)node << 6);

    // self row-slice: issue early, consumed in epilogue
    const uint4 selfv = *(const uint4*)(Xf + (size_t)node * F);

    float acc[8] = {};

    const int e0 = grp;
    const int nb = (cnt + STEP - 1) / STEP;   // pair-iterations (wave-uniform)

    unsigned pa0 = 0, pb0 = 0, pa1 = 0, pb1 = 0;
    uint4 va0 = {}, vb0 = {};
    if (nb > 0) {
        int ea = e0, eb = e0 + GRP;
        pa0 = (ea < cnt) ? erow[ea] : 0u;
        pb0 = (eb < cnt) ? erow[eb] : 0u;
        va0 = *(const uint4*)(Xf + (size_t)(pa0 & 0xffffu) * F);
        vb0 = *(const uint4*)(Xf + (size_t)(pb0 & 0xffffu) * F);
        if (nb > 1) {
            int ea1 = e0 + STEP, eb1 = ea1 + GRP;
            pa1 = (ea1 < cnt) ? erow[ea1] : 0u;
            pb1 = (eb1 < cnt) ? erow[eb1] : 0u;
        }
    }
    for (int p = 0; p < nb; ++p) {
        uint4 va1 = {}, vb1 = {};
        unsigned pa2 = 0, pb2 = 0;
        if (p + 1 < nb) {
            va1 = *(const uint4*)(Xf + (size_t)(pa1 & 0xffffu) * F);
            vb1 = *(const uint4*)(Xf + (size_t)(pb1 & 0xffffu) * F);
            if (p + 2 < nb) {
                int ea = e0 + (p + 2) * STEP, eb = ea + GRP;
                pa2 = (ea < cnt) ? erow[ea] : 0u;
                pb2 = (eb < cnt) ? erow[eb] : 0u;
            }
        }
        accum8(acc, b2f((unsigned short)(pa0 >> 16)), va0);
        accum8(acc, b2f((unsigned short)(pb0 >> 16)), vb0);
        pa0 = pa1; pb0 = pb1; va0 = va1; vb0 = vb1;
        pa1 = pa2; pb1 = pb2;
    }

    // cross-group reduce
    #pragma unroll
    for (int j = 0; j < 8; ++j) {
        if constexpr (GRP == 4) acc[j] += __shfl_xor(acc[j], 16, 64);
        acc[j] += __shfl_xor(acc[j], 32, 64);
    }

    if (grp == 0) {
        unsigned w[4] = {selfv.x, selfv.y, selfv.z, selfv.w};
        unsigned o[4];
        #pragma unroll
        for (int i = 0; i < 4; ++i) {
            float s0 = __uint_as_float(w[i] << 16);
            float s1 = __uint_as_float(w[i] & 0xffff0000u);
            unsigned short c0 = f2b(di * (acc[2 * i] + s0));
            unsigned short c1 = f2b(di * (acc[2 * i + 1] + s1));
            o[i] = (unsigned)c0 | ((unsigned)c1 << 16);
        }
        uint4 ov; ov.x = o[0]; ov.y = o[1]; ov.z = o[2]; ov.w = o[3];
        *(uint4*)(Z + (size_t)node * F + fo) = ov;
    }
}

// ---------- m97-structure GEMM, 2-phase double-buffered (T3-minimum) ----------
// 128x128 tile, 4 waves (2x2), each 64x64 = 4x4 16x16x32 fragments. BK=32.
// Double-buffered linear LDS [2][128][32]; next tile's global_load_lds issued BEFORE
// current tile's ds_read+MFMA -> loads fly under compute; one vmcnt-drain barrier/tile.
// A rows readable up to next multiple of 128 (NPAD); OOB-row garbage only pollutes
// accumulators discarded by row<M guards.
// Bijective XCD chunking (m204): each XCD owns a contiguous m-range for all n-blocks.
// CMODE 0: bf16 store + relu + optional rscale. 2: fused per-graph relu+max-pool.
template <int CMODE>
__global__ __launch_bounds__(256) void k_gemm128(const unsigned short* __restrict__ A,
                                                 const unsigned short* __restrict__ WT,
                                                 const float* __restrict__ bias,
                                                 unsigned short* __restrict__ C,
                                                 const int* __restrict__ batch,
                                                 int* __restrict__ gp,
                                                 const float* __restrict__ rscale,
                                                 int M, int N, int K) {
    __shared__ unsigned short As[2][128 * 32];
    __shared__ unsigned short Bs[2][128 * 32];
    const int tid = threadIdx.x;

    // bijective XCD remap of flat block id (xcd = f % 8 under round-robin dispatch)
    const int nwg = gridDim.x * gridDim.y;
    const int f = blockIdx.y * gridDim.x + blockIdx.x;
    const int q = nwg >> 3, r = nwg & 7;
    const int xcd = f & 7, idx = f >> 3;
    const int w = (xcd < r) ? xcd * (q + 1) + idx : r * (q + 1) + (xcd - r) * q + idx;
    const int m0 = (w / gridDim.x) * 128;
    const int n0 = (w % gridDim.x) * 128;

    const int wave = tid >> 6, lane = tid & 63;
    const int wm = (wave >> 1) * 64, wn = (wave & 1) * 64;
    const int quad = lane >> 4, mrow = lane & 15;

    const int sr = tid >> 2;              // staging row 0..63
    const int sc = (tid & 3) * 8;         // staging col (shorts)
    const unsigned short* Ag0 = A + (size_t)(m0 + sr) * K + sc;
    const unsigned short* Ag1 = A + (size_t)(m0 + 64 + sr) * K + sc;
    const unsigned short* Bg0 = WT + (size_t)(n0 + sr) * K + sc;
    const unsigned short* Bg1 = WT + (size_t)(n0 + 64 + sr) * K + sc;
    const int so0 = sr * 32 + sc, so1 = (64 + sr) * 32 + sc;

    f32x4 acc[4][4] = {};
    const int nsteps = K >> 5;

    // prologue: stage tile 0 into buffer 0
    GLOAD16(Ag0, &As[0][so0]);
    GLOAD16(Ag1, &As[0][so1]);
    GLOAD16(Bg0, &Bs[0][so0]);
    GLOAD16(Bg1, &Bs[0][so1]);
    __syncthreads();   // vmcnt(0) drain + barrier

    for (int step = 0; step < nsteps; ++step) {
        const int cur = step & 1;
        if (step + 1 < nsteps) {           // issue next tile while computing current
            const int k1 = (step + 1) << 5;
            GLOAD16(Ag0 + k1, &As[cur ^ 1][so0]);
            GLOAD16(Ag1 + k1, &As[cur ^ 1][so1]);
            GLOAD16(Bg0 + k1, &Bs[cur ^ 1][so0]);
            GLOAD16(Bg1 + k1, &Bs[cur ^ 1][so1]);
        }
        bf16x8 af[4], bf[4];
        #pragma unroll
        for (int mt = 0; mt < 4; ++mt)
            af[mt] = *(const bf16x8*)&As[cur][(wm + mt * 16 + mrow) * 32 + quad * 8];
        #pragma unroll
        for (int nt = 0; nt < 4; ++nt)
            bf[nt] = *(const bf16x8*)&Bs[cur][(wn + nt * 16 + mrow) * 32 + quad * 8];
        #pragma unroll
        for (int mt = 0; mt < 4; ++mt)
            #pragma unroll
            for (int nt = 0; nt < 4; ++nt)
                acc[mt][nt] = __builtin_amdgcn_mfma_f32_16x16x32_bf16(af[mt], bf[nt], acc[mt][nt], 0, 0, 0);
        __syncthreads();   // drains prefetch vmcnt + this tile's lgkm; gates buffer reuse
    }

    float bn[4];
    #pragma unroll
    for (int nt = 0; nt < 4; ++nt) bn[nt] = bias[n0 + wn + nt * 16 + mrow];

    if constexpr (CMODE == 0) {
        #pragma unroll
        for (int mt = 0; mt < 4; ++mt) {
            #pragma unroll
            for (int r4 = 0; r4 < 4; ++r4) {
                int row = m0 + wm + mt * 16 + quad * 4 + r4;
                if (row < M) {
                    float rs = rscale ? rscale[row] : 1.0f;
                    #pragma unroll
                    for (int nt = 0; nt < 4; ++nt) {
                        float v = fmaxf(acc[mt][nt][r4] + bn[nt], 0.f) * rs;
                        C[(size_t)row * N + n0 + wn + nt * 16 + mrow] = f2b(v);
                    }
                }
            }
        }
    } else {
        // per-wave pool: wave covers 64 rows -> spans <=2 graphs (min graph size 97)
        const int wr0 = m0 + wm;
        int g0i = wr0 < M ? wr0 : M - 1;
        const int g0 = batch[g0i];
        int lastr = wr0 + 63; if (lastr >= M) lastr = M - 1;
        const int gl = batch[lastr];
        bool rok[16]; int gid[16];
        #pragma unroll
        for (int mt = 0; mt < 4; ++mt)
            #pragma unroll
            for (int r4 = 0; r4 < 4; ++r4) {
                int row = wr0 + mt * 16 + quad * 4 + r4;
                rok[mt * 4 + r4] = row < M;
                gid[mt * 4 + r4] = (row < M) ? batch[row] : -1;
            }
        #pragma unroll
        for (int nt = 0; nt < 4; ++nt) {
            float v0 = 0.f, v1 = 0.f;
            #pragma unroll
            for (int mt = 0; mt < 4; ++mt)
                #pragma unroll
                for (int r4 = 0; r4 < 4; ++r4)
                    if (rok[mt * 4 + r4]) {
                        float v = fmaxf(acc[mt][nt][r4] + bn[nt], 0.f);
                        if (gid[mt * 4 + r4] == g0) v0 = fmaxf(v0, v);
                        else v1 = fmaxf(v1, v);
                    }
            v0 = fmaxf(v0, __shfl_xor(v0, 16, 64));
            v0 = fmaxf(v0, __shfl_xor(v0, 32, 64));
            v1 = fmaxf(v1, __shfl_xor(v1, 16, 64));
            v1 = fmaxf(v1, __shfl_xor(v1, 32, 64));
            if (quad == 0) {
                int c = n0 + wn + nt * 16 + mrow;
                atomicMax(&gp[(size_t)g0 * N + c], __float_as_int(v0));
                if (gl != g0) atomicMax(&gp[(size_t)gl * N + c], __float_as_int(v1));
            }
        }
    }
}

// ---------- legacy GEMM for the small MLP head (M=512) ----------
// block 64(M) x 128(N), 4 waves (2x2 of 32x64), BK=32, 16x16x32 MFMA.
// CMODE 0: bf16 store + relu. 1: fp32 store, no relu. AFP: A is fp32.
template <int CMODE, int AFP>
__global__ __launch_bounds__(256) void k_gemm_mfma(const void* __restrict__ Av,
                                                   const unsigned short* __restrict__ WT,
                                                   const float* __restrict__ bias,
                                                   void* __restrict__ Cv,
                                                   int M, int N, int K) {
    constexpr int LDK = 40;
    __shared__ unsigned short As[64 * LDK];
    __shared__ unsigned short Bs[128 * LDK];
    const int tid = threadIdx.x;
    const int m0 = blockIdx.y * 64, n0 = blockIdx.x * 128;
    const int wave = tid >> 6, lane = tid & 63;
    const int wm = (wave >> 1) * 32;
    const int wn = (wave & 1) * 64;
    const int quad = lane >> 4, mrow = lane & 15;

    const int ar = tid >> 2;
    const int ak = (tid & 3) * 8;
    const bool arow_ok = (m0 + ar) < M;
    const size_t aoff = (size_t)(m0 + ar) * K + ak;
    const unsigned short* Bg0 = WT + (size_t)(n0 + ar) * K + ak;
    const unsigned short* Bg1 = WT + (size_t)(n0 + ar + 64) * K + ak;

    f32x4 acc[2][4] = {};

    for (int k0 = 0; k0 < K; k0 += 32) {
        u16x8 av = {};
        if (arow_ok) {
            if constexpr (AFP) {
                const float* Af = (const float*)Av + aoff + k0;
                float4 f0 = *(const float4*)Af;
                float4 f1 = *(const float4*)(Af + 4);
                av[0] = (short)f2b(f0.x); av[1] = (short)f2b(f0.y);
                av[2] = (short)f2b(f0.z); av[3] = (short)f2b(f0.w);
                av[4] = (short)f2b(f1.x); av[5] = (short)f2b(f1.y);
                av[6] = (short)f2b(f1.z); av[7] = (short)f2b(f1.w);
            } else {
                av = *(const u16x8*)((const unsigned short*)Av + aoff + k0);
            }
        }
        u16x8 bv0 = *(const u16x8*)(Bg0 + k0);
        u16x8 bv1 = *(const u16x8*)(Bg1 + k0);
        *(u16x8*)&As[ar * LDK + ak] = av;
        *(u16x8*)&Bs[ar * LDK + ak] = bv0;
        *(u16x8*)&Bs[(ar + 64) * LDK + ak] = bv1;
        __syncthreads();
        bf16x8 af[2], bf[4];
        #pragma unroll
        for (int mt = 0; mt < 2; ++mt)
            af[mt] = *(const bf16x8*)&As[(wm + mt * 16 + mrow) * LDK + quad * 8];
        #pragma unroll
        for (int nt = 0; nt < 4; ++nt)
            bf[nt] = *(const bf16x8*)&Bs[(wn + nt * 16 + mrow) * LDK + quad * 8];
        #pragma unroll
        for (int mt = 0; mt < 2; ++mt)
            #pragma unroll
            for (int nt = 0; nt < 4; ++nt)
                acc[mt][nt] = __builtin_amdgcn_mfma_f32_16x16x32_bf16(af[mt], bf[nt], acc[mt][nt], 0, 0, 0);
        __syncthreads();
    }

    float bn[4];
    #pragma unroll
    for (int nt = 0; nt < 4; ++nt) bn[nt] = bias[n0 + wn + nt * 16 + mrow];

    if constexpr (CMODE == 0) {
        unsigned short* C = (unsigned short*)Cv;
        #pragma unroll
        for (int mt = 0; mt < 2; ++mt) {
            #pragma unroll
            for (int r = 0; r < 4; ++r) {
                int row = m0 + wm + mt * 16 + quad * 4 + r;
                if (row < M) {
                    #pragma unroll
                    for (int nt = 0; nt < 4; ++nt) {
                        float v = fmaxf(acc[mt][nt][r] + bn[nt], 0.f);
                        C[(size_t)row * N + n0 + wn + nt * 16 + mrow] = f2b(v);
                    }
                }
            }
        }
    } else {
        float* C = (float*)Cv;
        #pragma unroll
        for (int mt = 0; mt < 2; ++mt) {
            #pragma unroll
            for (int r = 0; r < 4; ++r) {
                int row = m0 + wm + mt * 16 + quad * 4 + r;
                if (row < M) {
                    #pragma unroll
                    for (int nt = 0; nt < 4; ++nt)
                        C[(size_t)row * N + n0 + wn + nt * 16 + mrow] = acc[mt][nt][r] + bn[nt];
                }
            }
        }
    }
}

extern "C" void kernel_launch(void* const* d_in, const int* in_sizes, int n_in,
                              void* d_out, int out_size, void* d_ws, size_t ws_size,
                              hipStream_t stream) {
    const float* x   = (const float*)d_in[0];
    const float* ew  = (const float*)d_in[1];
    const float* W1  = (const float*)d_in[2];
    const float* b1  = (const float*)d_in[3];
    const float* W2  = (const float*)d_in[4];
    const float* b2  = (const float*)d_in[5];
    const float* W3  = (const float*)d_in[6];
    const float* b3  = (const float*)d_in[7];
    const float* Wf1 = (const float*)d_in[8];
    const float* bf1 = (const float*)d_in[9];
    const float* Wf2 = (const float*)d_in[10];
    const float* bf2 = (const float*)d_in[11];
    const int* ei    = (const int*)d_in[12];
    const int* batch = (const int*)d_in[13];
    float* out = (float*)d_out;
    (void)in_sizes; (void)n_in; (void)out_size; (void)ws_size;

    char* p = (char*)d_ws;
    auto alloc = [&](size_t bytes) -> char* {
        char* r = p;
        p += (bytes + 255) & ~(size_t)255;
        return r;
    };
    u64*   deg_cnt = (u64*)alloc((size_t)NNODES * 64);   // one 64B line per node
    float* dinv   = (float*)alloc((size_t)NNODES * 4);
    unsigned* edges = (unsigned*)alloc((size_t)NNODES * DCAP * 4);  // padded CSR, 12.8 MB
    int*   gp     = (int*)  alloc((size_t)NGRAPH * 512 * 4);
    unsigned short* f1   = (unsigned short*)alloc((size_t)NGRAPH * 1024 * 2);
    unsigned short* wt1  = (unsigned short*)alloc((size_t)128 * 128 * 2);
    unsigned short* wt2  = (unsigned short*)alloc((size_t)256 * 128 * 2);
    unsigned short* wt3  = (unsigned short*)alloc((size_t)512 * 256 * 2);
    unsigned short* wtf1 = (unsigned short*)alloc((size_t)1024 * 512 * 2);
    unsigned short* wtf2 = (unsigned short*)alloc((size_t)128 * 1024 * 2);
    unsigned short* bufA = (unsigned short*)alloc((size_t)NPAD * 256 * 2);
    unsigned short* bufB = (unsigned short*)alloc((size_t)NPAD * 256 * 2);
    unsigned short* x16  = bufB;   // consumed by agg-1 before gemm-1 overwrites bufB
    // total ~71 MB

    const int MB128 = (NNODES + 127) / 128; // 391
    const int AGG = (NNODES + 3) / 4;       // 12500
    const int EB = (NEDGES + 255) / 256;    // 3125 edge blocks

    // graph preprocessing: 2 memsets + 2 kernels
    hipMemsetAsync(deg_cnt, 0, (size_t)NNODES * 64, stream);
    hipMemsetAsync(gp, 0, (size_t)NGRAPH * 512 * 4, stream);
    k_graph<<<204 + EB, 256, 0, stream>>>(W1, W2, W3, Wf1, Wf2,
                                          wt1, wt2, wt3, wtf1, wtf2,
                                          ei, ei + NEDGES, ew, deg_cnt, edges);
    k_cvt_prep<<<(NNODES * 32 + 255) / 256, 256, 0, stream>>>(x, deg_cnt, dinv, x16, NNODES * 32);

    // layer 1: Z1 = dinv*(x' + A@x'); h1' = dinv*relu(Z1@W1+b1)
    k_aggregate<128, 1><<<AGG, 256, 0, stream>>>(x16, deg_cnt, edges, dinv, bufA);
    k_gemm128<0><<<dim3(1, MB128), 256, 0, stream>>>(bufA, wt1, b1, bufB, nullptr, nullptr, dinv, NNODES, 128, 128);
    // layer 2
    k_aggregate<128, 1><<<AGG, 256, 0, stream>>>(bufB, deg_cnt, edges, dinv, bufA);
    k_gemm128<0><<<dim3(2, MB128), 256, 0, stream>>>(bufA, wt2, b2, bufB, nullptr, nullptr, dinv, NNODES, 256, 128);
    // layer 3 + fused pool (unscaled relu feeds the pool); feature-sliced aggregate (S=2)
    k_aggregate<256, 2><<<AGG * 2, 256, 0, stream>>>(bufB, deg_cnt, edges, dinv, bufA);
    k_gemm128<2><<<dim3(4, MB128), 256, 0, stream>>>(bufA, wt3, b3, nullptr, batch, gp, nullptr, NNODES, 512, 256);

    // MLP head (legacy kernel, M=512)
    k_gemm_mfma<0, 1><<<dim3(8, NGRAPH / 64), 256, 0, stream>>>(gp, wtf1, bf1, f1, NGRAPH, 1024, 512);
    k_gemm_mfma<1, 0><<<dim3(1, NGRAPH / 64), 256, 0, stream>>>(f1, wtf2, bf2, out, NGRAPH, 128, 1024);
}

// Round 10
// 364.918 us; speedup vs baseline: 1.0330x; 1.0330x over previous
//
#include <hip/hip_runtime.h>

#define NNODES 50000
#define NPAD   50048   // 391 * 128; padded row count so 128-tile GEMM staging never faults
#define NEDGES 800000
#define NGRAPH 512
#define DCAP 64   // padded edge slots per node; Poisson(16) max ~37, P(>=64) ~ 1e-23

typedef short bf16x8 __attribute__((ext_vector_type(8)));
typedef unsigned short u16x8 __attribute__((ext_vector_type(8)));
typedef float f32x4 __attribute__((ext_vector_type(4)));
typedef unsigned long long u64;

// async global->LDS, 16B per lane (dest = wave-uniform base + lane*16, linear layout)
#define GLOAD16(g, l)                                                                 \
    __builtin_amdgcn_global_load_lds((const __attribute__((address_space(1))) unsigned*)(g), \
                                     (__attribute__((address_space(3))) unsigned*)(l), 16, 0, 0)

// ---------- bf16 <-> fp32 helpers ----------
static __device__ __forceinline__ float b2f(unsigned short u) {
    return __uint_as_float(((unsigned)u) << 16);
}
static __device__ __forceinline__ unsigned short f2b(float f) {
    unsigned u = __float_as_uint(f);
    unsigned r = (u + 0x7fffu + ((u >> 16) & 1u)) >> 16;  // round-nearest-even
    return (unsigned short)r;
}

// accumulate 8 bf16 (packed in uint4) * c into acc[8]
static __device__ __forceinline__ void accum8(float (&acc)[8], float c, uint4 v) {
    unsigned w[4] = {v.x, v.y, v.z, v.w};
    #pragma unroll
    for (int i = 0; i < 4; ++i) {
        acc[2 * i]     += c * __uint_as_float(w[i] << 16);
        acc[2 * i + 1] += c * __uint_as_float(w[i] & 0xffff0000u);
    }
}

// ---------- fused preprocessing under the atomic wall ----------
// Edge placement is memory-side atomic/scatter-store throughput-bound (~60us, all pipes
// idle: r8 26% occ = r9 59% occ). So: edge blocks FIRST (r8's 4-edge/thread ILP form,
// packed u64 deg_cnt), then weight transposes, then UNSCALED x->bf16 conversion —
// ~38MB of streaming work that rides under the wall for free.
#define EBLK 782   // ceil(200000/256) edge blocks (4 edges/thread)
__global__ __launch_bounds__(256) void k_pre(const float* __restrict__ W1, const float* __restrict__ W2,
                                             const float* __restrict__ W3, const float* __restrict__ Wf1,
                                             const float* __restrict__ Wf2,
                                             unsigned short* __restrict__ T1, unsigned short* __restrict__ T2,
                                             unsigned short* __restrict__ T3, unsigned short* __restrict__ Tf1,
                                             unsigned short* __restrict__ Tf2,
                                             const int4* __restrict__ ei_s, const int4* __restrict__ ei_d,
                                             const float4* __restrict__ ew4,
                                             u64* deg_cnt, unsigned* __restrict__ edges,
                                             const float* __restrict__ x, unsigned short* __restrict__ x16) {
    const int b = blockIdx.x;
    if (b < EBLK) {
        // edge placement: u64 atomic returns old count = this edge's slot; 4 chains/thread
        int t = b * 256 + threadIdx.x;
        if (t >= NEDGES / 4) return;
        int4 ss = ei_s[t];
        int4 dd = ei_d[t];
        float4 ww = ew4[t];
        int s[4] = {ss.x, ss.y, ss.z, ss.w};
        int d[4] = {dd.x, dd.y, dd.z, dd.w};
        float w[4] = {ww.x, ww.y, ww.z, ww.w};
        int slot[4];
        #pragma unroll
        for (int u = 0; u < 4; ++u) {
            unsigned fixed = __float2uint_rn(w[u] * 16777216.0f);  // 8.24 fixed; ew in [0,1)
            u64 old = atomicAdd(&deg_cnt[d[u]], ((u64)1 << 32) | fixed);
            slot[u] = (int)(old >> 32);
            if (slot[u] > DCAP - 1) slot[u] = DCAP - 1;  // never fires (safety)
        }
        #pragma unroll
        for (int u = 0; u < 4; ++u)
            edges[((unsigned)d[u] << 6) | slot[u]] = ((unsigned)f2b(w[u]) << 16) | (unsigned)s[u];
        return;
    }
    if (b < EBLK + 204) {
        // W[K][N] fp32 -> WT[N][K] bf16, 64x64 LDS tile, both global sides coalesced
        const int bb = b - EBLK;
        const float* W; unsigned short* T; int K, N, t0;
        if (bb < 4)        { W = W1;  T = T1;  K = 128;  N = 128;  t0 = 0;   }
        else if (bb < 12)  { W = W2;  T = T2;  K = 128;  N = 256;  t0 = 4;   }
        else if (bb < 44)  { W = W3;  T = T3;  K = 256;  N = 512;  t0 = 12;  }
        else if (bb < 172) { W = Wf1; T = Tf1; K = 512;  N = 1024; t0 = 44;  }
        else               { W = Wf2; T = Tf2; K = 1024; N = 128;  t0 = 172; }
        const int tile = bb - t0;
        const int ntn = N >> 6;
        const int k0 = (tile / ntn) * 64, n0 = (tile % ntn) * 64;
        __shared__ float sm[64][65];
        const int t = threadIdx.x;
        const int rr = t >> 6, cc = t & 63;
        #pragma unroll
        for (int r = 0; r < 16; ++r) {
            int kl = r * 4 + rr;
            sm[kl][cc] = W[(size_t)(k0 + kl) * N + n0 + cc];
        }
        __syncthreads();
        #pragma unroll
        for (int r = 0; r < 16; ++r) {
            int nl = r * 4 + rr;
            T[(size_t)(n0 + nl) * K + k0 + cc] = f2b(sm[cc][nl]);
        }
        return;
    }
    // UNSCALED x fp32 -> bf16 (8 floats/thread); dinv[s] applied per-edge in agg layer 1
    int idx = (b - EBLK - 204) * 256 + threadIdx.x;
    if (idx < NNODES * 16) {
        float4 v0 = ((const float4*)x)[idx * 2];
        float4 v1 = ((const float4*)x)[idx * 2 + 1];
        uint4 o;
        o.x = (unsigned)f2b(v0.x) | ((unsigned)f2b(v0.y) << 16);
        o.y = (unsigned)f2b(v0.z) | ((unsigned)f2b(v0.w) << 16);
        o.z = (unsigned)f2b(v1.x) | ((unsigned)f2b(v1.y) << 16);
        o.w = (unsigned)f2b(v1.z) | ((unsigned)f2b(v1.w) << 16);
        ((uint4*)x16)[idx] = o;
    }
}

// dinv from packed degree (+1.0 self-loop folded in) + gp zero
__global__ void k_prep(const u64* __restrict__ deg_cnt, float* __restrict__ dinv, int* __restrict__ gp) {
    int i = blockIdx.x * 256 + threadIdx.x;
    if (i < NNODES)
        dinv[i] = rsqrtf((float)(unsigned)(deg_cnt[i] & 0xffffffffull) * 5.9604645e-8f + 1.0f);
    if (i < NGRAPH * 512) gp[i] = 0;   // +0.0f bits; relu pool >= 0
}

// ---------- aggregation: Z[d,:] = dinv[d] * (X'[d,:] + sum_e c_e * X'[src_e,:]) ----------
// wave-per-(node, feature-slice). SLICES=2 (F=256): slice parity == XCD parity under
// round-robin dispatch -> 12.8MB half-table per XCD L2 (r8: FETCH 187->162MB).
// DSRC: X is UNSCALED -> c_e = w_e * dinv[src] (broadcast 4B load, pipelined one stage
// ahead) and self term scaled by dinv[node]. 16B dwordx4 gathers, rotating 2-deep
// pipeline, weight-0 masked tail, cross-group shfl reduce, 16B stores by group 0.
template <int F, int SLICES, bool DSRC>
__global__ __launch_bounds__(256) void k_aggregate(const unsigned short* __restrict__ X,
                                                   const u64* __restrict__ deg_cnt,
                                                   const unsigned* __restrict__ edges,
                                                   const float* __restrict__ dinv,
                                                   unsigned short* __restrict__ Z) {
    constexpr int FS = F / SLICES;     // features handled per block
    constexpr int LPR = FS / 8;        // lanes per source row-slice (16 or 32)
    constexpr int GRP = 64 / LPR;      // edges per step (4 or 2)
    constexpr int STEP = GRP * 2;      // edges per pair-iteration (8 or 4)
    const int bid = blockIdx.x;
    const int slice = (SLICES == 1) ? 0 : (bid & (SLICES - 1));
    const int chunk = (SLICES == 1) ? bid : (bid / SLICES);
    const int wave = threadIdx.x >> 6, lane = threadIdx.x & 63;
    const int node = chunk * 4 + wave;
    if (node >= NNODES) return;
    const int sub = lane & (LPR - 1);
    const int grp = lane / LPR;
    const int fo = slice * FS + sub * 8;
    const unsigned short* Xf = X + fo;
    const float di = dinv[node];
    const int cnt = (int)(deg_cnt[node] >> 32);
    const unsigned* erow = edges + ((unsigned)node << 6);

    // self row-slice: issue early, consumed in epilogue
    const uint4 selfv = *(const uint4*)(Xf + (size_t)node * F);

    float acc[8] = {};

    const int e0 = grp;
    const int nb = (cnt + STEP - 1) / STEP;   // pair-iterations (wave-uniform)

    unsigned pa0 = 0, pb0 = 0, pa1 = 0, pb1 = 0;
    uint4 va0 = {}, vb0 = {};
    float da0 = 1.f, db0 = 1.f;
    if (nb > 0) {
        int ea = e0, eb = e0 + GRP;
        pa0 = (ea < cnt) ? erow[ea] : 0u;
        pb0 = (eb < cnt) ? erow[eb] : 0u;
        va0 = *(const uint4*)(Xf + (size_t)(pa0 & 0xffffu) * F);
        vb0 = *(const uint4*)(Xf + (size_t)(pb0 & 0xffffu) * F);
        if constexpr (DSRC) { da0 = dinv[pa0 & 0xffffu]; db0 = dinv[pb0 & 0xffffu]; }
        if (nb > 1) {
            int ea1 = e0 + STEP, eb1 = ea1 + GRP;
            pa1 = (ea1 < cnt) ? erow[ea1] : 0u;
            pb1 = (eb1 < cnt) ? erow[eb1] : 0u;
        }
    }
    for (int p = 0; p < nb; ++p) {
        uint4 va1 = {}, vb1 = {};
        float da1 = 1.f, db1 = 1.f;
        unsigned pa2 = 0, pb2 = 0;
        if (p + 1 < nb) {
            va1 = *(const uint4*)(Xf + (size_t)(pa1 & 0xffffu) * F);
            vb1 = *(const uint4*)(Xf + (size_t)(pb1 & 0xffffu) * F);
            if constexpr (DSRC) { da1 = dinv[pa1 & 0xffffu]; db1 = dinv[pb1 & 0xffffu]; }
            if (p + 2 < nb) {
                int ea = e0 + (p + 2) * STEP, eb = ea + GRP;
                pa2 = (ea < cnt) ? erow[ea] : 0u;
                pb2 = (eb < cnt) ? erow[eb] : 0u;
            }
        }
        float ca = b2f((unsigned short)(pa0 >> 16));
        float cb = b2f((unsigned short)(pb0 >> 16));
        if constexpr (DSRC) { ca *= da0; cb *= db0; }
        accum8(acc, ca, va0);
        accum8(acc, cb, vb0);
        pa0 = pa1; pb0 = pb1; va0 = va1; vb0 = vb1;
        da0 = da1; db0 = db1;
        pa1 = pa2; pb1 = pb2;
    }

    // cross-group reduce
    #pragma unroll
    for (int j = 0; j < 8; ++j) {
        if constexpr (GRP == 4) acc[j] += __shfl_xor(acc[j], 16, 64);
        acc[j] += __shfl_xor(acc[j], 32, 64);
    }

    if (grp == 0) {
        const float sc = DSRC ? di : 1.0f;   // self term scale (unscaled X path)
        unsigned w[4] = {selfv.x, selfv.y, selfv.z, selfv.w};
        unsigned o[4];
        #pragma unroll
        for (int i = 0; i < 4; ++i) {
            float s0 = __uint_as_float(w[i] << 16);
            float s1 = __uint_as_float(w[i] & 0xffff0000u);
            unsigned short c0 = f2b(di * (acc[2 * i] + sc * s0));
            unsigned short c1 = f2b(di * (acc[2 * i + 1] + sc * s1));
            o[i] = (unsigned)c0 | ((unsigned)c1 << 16);
        }
        uint4 ov; ov.x = o[0]; ov.y = o[1]; ov.z = o[2]; ov.w = o[3];
        *(uint4*)(Z + (size_t)node * F + fo) = ov;
    }
}

// ---------- m97-structure GEMM, 2-phase double-buffered (T3-minimum) ----------
// 128x128 tile, 4 waves (2x2), each 64x64 = 4x4 16x16x32 fragments. BK=32.
// Double-buffered linear LDS [2][128][32]; next tile's global_load_lds issued BEFORE
// current tile's ds_read+MFMA; one vmcnt-drain barrier/tile. NPAD covers staging OOB.
// Bijective XCD chunking (m204): each XCD owns a contiguous m-range for all n-blocks.
// CMODE 0: bf16 store + relu + optional rscale. 2: fused per-graph relu+max-pool.
template <int CMODE>
__global__ __launch_bounds__(256) void k_gemm128(const unsigned short* __restrict__ A,
                                                 const unsigned short* __restrict__ WT,
                                                 const float* __restrict__ bias,
                                                 unsigned short* __restrict__ C,
                                                 const int* __restrict__ batch,
                                                 int* __restrict__ gp,
                                                 const float* __restrict__ rscale,
                                                 int M, int N, int K) {
    __shared__ unsigned short As[2][128 * 32];
    __shared__ unsigned short Bs[2][128 * 32];
    const int tid = threadIdx.x;

    // bijective XCD remap of flat block id (xcd = f % 8 under round-robin dispatch)
    const int nwg = gridDim.x * gridDim.y;
    const int f = blockIdx.y * gridDim.x + blockIdx.x;
    const int q = nwg >> 3, r = nwg & 7;
    const int xcd = f & 7, idx = f >> 3;
    const int w = (xcd < r) ? xcd * (q + 1) + idx : r * (q + 1) + (xcd - r) * q + idx;
    const int m0 = (w / gridDim.x) * 128;
    const int n0 = (w % gridDim.x) * 128;

    const int wave = tid >> 6, lane = tid & 63;
    const int wm = (wave >> 1) * 64, wn = (wave & 1) * 64;
    const int quad = lane >> 4, mrow = lane & 15;

    const int sr = tid >> 2;              // staging row 0..63
    const int sc = (tid & 3) * 8;         // staging col (shorts)
    const unsigned short* Ag0 = A + (size_t)(m0 + sr) * K + sc;
    const unsigned short* Ag1 = A + (size_t)(m0 + 64 + sr) * K + sc;
    const unsigned short* Bg0 = WT + (size_t)(n0 + sr) * K + sc;
    const unsigned short* Bg1 = WT + (size_t)(n0 + 64 + sr) * K + sc;
    const int so0 = sr * 32 + sc, so1 = (64 + sr) * 32 + sc;

    f32x4 acc[4][4] = {};
    const int nsteps = K >> 5;

    // prologue: stage tile 0 into buffer 0
    GLOAD16(Ag0, &As[0][so0]);
    GLOAD16(Ag1, &As[0][so1]);
    GLOAD16(Bg0, &Bs[0][so0]);
    GLOAD16(Bg1, &Bs[0][so1]);
    __syncthreads();   // vmcnt(0) drain + barrier

    for (int step = 0; step < nsteps; ++step) {
        const int cur = step & 1;
        if (step + 1 < nsteps) {           // issue next tile while computing current
            const int k1 = (step + 1) << 5;
            GLOAD16(Ag0 + k1, &As[cur ^ 1][so0]);
            GLOAD16(Ag1 + k1, &As[cur ^ 1][so1]);
            GLOAD16(Bg0 + k1, &Bs[cur ^ 1][so0]);
            GLOAD16(Bg1 + k1, &Bs[cur ^ 1][so1]);
        }
        bf16x8 af[4], bf[4];
        #pragma unroll
        for (int mt = 0; mt < 4; ++mt)
            af[mt] = *(const bf16x8*)&As[cur][(wm + mt * 16 + mrow) * 32 + quad * 8];
        #pragma unroll
        for (int nt = 0; nt < 4; ++nt)
            bf[nt] = *(const bf16x8*)&Bs[cur][(wn + nt * 16 + mrow) * 32 + quad * 8];
        #pragma unroll
        for (int mt = 0; mt < 4; ++mt)
            #pragma unroll
            for (int nt = 0; nt < 4; ++nt)
                acc[mt][nt] = __builtin_amdgcn_mfma_f32_16x16x32_bf16(af[mt], bf[nt], acc[mt][nt], 0, 0, 0);
        __syncthreads();   // drains prefetch vmcnt + this tile's lgkm; gates buffer reuse
    }

    float bn[4];
    #pragma unroll
    for (int nt = 0; nt < 4; ++nt) bn[nt] = bias[n0 + wn + nt * 16 + mrow];

    if constexpr (CMODE == 0) {
        #pragma unroll
        for (int mt = 0; mt < 4; ++mt) {
            #pragma unroll
            for (int r4 = 0; r4 < 4; ++r4) {
                int row = m0 + wm + mt * 16 + quad * 4 + r4;
                if (row < M) {
                    float rs = rscale ? rscale[row] : 1.0f;
                    #pragma unroll
                    for (int nt = 0; nt < 4; ++nt) {
                        float v = fmaxf(acc[mt][nt][r4] + bn[nt], 0.f) * rs;
                        C[(size_t)row * N + n0 + wn + nt * 16 + mrow] = f2b(v);
                    }
                }
            }
        }
    } else {
        // per-wave pool: wave covers 64 rows -> spans <=2 graphs (min graph size 97)
        const int wr0 = m0 + wm;
        int g0i = wr0 < M ? wr0 : M - 1;
        const int g0 = batch[g0i];
        int lastr = wr0 + 63; if (lastr >= M) lastr = M - 1;
        const int gl = batch[lastr];
        bool rok[16]; int gid[16];
        #pragma unroll
        for (int mt = 0; mt < 4; ++mt)
            #pragma unroll
            for (int r4 = 0; r4 < 4; ++r4) {
                int row = wr0 + mt * 16 + quad * 4 + r4;
                rok[mt * 4 + r4] = row < M;
                gid[mt * 4 + r4] = (row < M) ? batch[row] : -1;
            }
        #pragma unroll
        for (int nt = 0; nt < 4; ++nt) {
            float v0 = 0.f, v1 = 0.f;
            #pragma unroll
            for (int mt = 0; mt < 4; ++mt)
                #pragma unroll
                for (int r4 = 0; r4 < 4; ++r4)
                    if (rok[mt * 4 + r4]) {
                        float v = fmaxf(acc[mt][nt][r4] + bn[nt], 0.f);
                        if (gid[mt * 4 + r4] == g0) v0 = fmaxf(v0, v);
                        else v1 = fmaxf(v1, v);
                    }
            v0 = fmaxf(v0, __shfl_xor(v0, 16, 64));
            v0 = fmaxf(v0, __shfl_xor(v0, 32, 64));
            v1 = fmaxf(v1, __shfl_xor(v1, 16, 64));
            v1 = fmaxf(v1, __shfl_xor(v1, 32, 64));
            if (quad == 0) {
                int c = n0 + wn + nt * 16 + mrow;
                atomicMax(&gp[(size_t)g0 * N + c], __float_as_int(v0));
                if (gl != g0) atomicMax(&gp[(size_t)gl * N + c], __float_as_int(v1));
            }
        }
    }
}

// ---------- legacy GEMM for the small MLP head (M=512) ----------
// block 64(M) x 128(N), 4 waves (2x2 of 32x64), BK=32, 16x16x32 MFMA.
// CMODE 0: bf16 store + relu. 1: fp32 store, no relu. AFP: A is fp32.
template <int CMODE, int AFP>
__global__ __launch_bounds__(256) void k_gemm_mfma(const void* __restrict__ Av,
                                                   const unsigned short* __restrict__ WT,
                                                   const float* __restrict__ bias,
                                                   void* __restrict__ Cv,
                                                   int M, int N, int K) {
    constexpr int LDK = 40;
    __shared__ unsigned short As[64 * LDK];
    __shared__ unsigned short Bs[128 * LDK];
    const int tid = threadIdx.x;
    const int m0 = blockIdx.y * 64, n0 = blockIdx.x * 128;
    const int wave = tid >> 6, lane = tid & 63;
    const int wm = (wave >> 1) * 32;
    const int wn = (wave & 1) * 64;
    const int quad = lane >> 4, mrow = lane & 15;

    const int ar = tid >> 2;
    const int ak = (tid & 3) * 8;
    const bool arow_ok = (m0 + ar) < M;
    const size_t aoff = (size_t)(m0 + ar) * K + ak;
    const unsigned short* Bg0 = WT + (size_t)(n0 + ar) * K + ak;
    const unsigned short* Bg1 = WT + (size_t)(n0 + ar + 64) * K + ak;

    f32x4 acc[2][4] = {};

    for (int k0 = 0; k0 < K; k0 += 32) {
        u16x8 av = {};
        if (arow_ok) {
            if constexpr (AFP) {
                const float* Af = (const float*)Av + aoff + k0;
                float4 f0 = *(const float4*)Af;
                float4 f1 = *(const float4*)(Af + 4);
                av[0] = (short)f2b(f0.x); av[1] = (short)f2b(f0.y);
                av[2] = (short)f2b(f0.z); av[3] = (short)f2b(f0.w);
                av[4] = (short)f2b(f1.x); av[5] = (short)f2b(f1.y);
                av[6] = (short)f2b(f1.z); av[7] = (short)f2b(f1.w);
            } else {
                av = *(const u16x8*)((const unsigned short*)Av + aoff + k0);
            }
        }
        u16x8 bv0 = *(const u16x8*)(Bg0 + k0);
        u16x8 bv1 = *(const u16x8*)(Bg1 + k0);
        *(u16x8*)&As[ar * LDK + ak] = av;
        *(u16x8*)&Bs[ar * LDK + ak] = bv0;
        *(u16x8*)&Bs[(ar + 64) * LDK + ak] = bv1;
        __syncthreads();
        bf16x8 af[2], bf[4];
        #pragma unroll
        for (int mt = 0; mt < 2; ++mt)
            af[mt] = *(const bf16x8*)&As[(wm + mt * 16 + mrow) * LDK + quad * 8];
        #pragma unroll
        for (int nt = 0; nt < 4; ++nt)
            bf[nt] = *(const bf16x8*)&Bs[(wn + nt * 16 + mrow) * LDK + quad * 8];
        #pragma unroll
        for (int mt = 0; mt < 2; ++mt)
            #pragma unroll
            for (int nt = 0; nt < 4; ++nt)
                acc[mt][nt] = __builtin_amdgcn_mfma_f32_16x16x32_bf16(af[mt], bf[nt], acc[mt][nt], 0, 0, 0);
        __syncthreads();
    }

    float bn[4];
    #pragma unroll
    for (int nt = 0; nt < 4; ++nt) bn[nt] = bias[n0 + wn + nt * 16 + mrow];

    if constexpr (CMODE == 0) {
        unsigned short* C = (unsigned short*)Cv;
        #pragma unroll
        for (int mt = 0; mt < 2; ++mt) {
            #pragma unroll
            for (int r = 0; r < 4; ++r) {
                int row = m0 + wm + mt * 16 + quad * 4 + r;
                if (row < M) {
                    #pragma unroll
                    for (int nt = 0; nt < 4; ++nt) {
                        float v = fmaxf(acc[mt][nt][r] + bn[nt], 0.f);
                        C[(size_t)row * N + n0 + wn + nt * 16 + mrow] = f2b(v);
                    }
                }
            }
        }
    } else {
        float* C = (float*)Cv;
        #pragma unroll
        for (int mt = 0; mt < 2; ++mt) {
            #pragma unroll
            for (int r = 0; r < 4; ++r) {
                int row = m0 + wm + mt * 16 + quad * 4 + r;
                if (row < M) {
                    #pragma unroll
                    for (int nt = 0; nt < 4; ++nt)
                        C[(size_t)row * N + n0 + wn + nt * 16 + mrow] = acc[mt][nt][r] + bn[nt];
                }
            }
        }
    }
}

extern "C" void kernel_launch(void* const* d_in, const int* in_sizes, int n_in,
                              void* d_out, int out_size, void* d_ws, size_t ws_size,
                              hipStream_t stream) {
    const float* x   = (const float*)d_in[0];
    const float* ew  = (const float*)d_in[1];
    const float* W1  = (const float*)d_in[2];
    const float* b1  = (const float*)d_in[3];
    const float* W2  = (const float*)d_in[4];
    const float* b2  = (const float*)d_in[5];
    const float* W3  = (const float*)d_in[6];
    const float* b3  = (const float*)d_in[7];
    const float* Wf1 = (const float*)d_in[8];
    const float* bf1 = (const float*)d_in[9];
    const float* Wf2 = (const float*)d_in[10];
    const float* bf2 = (const float*)d_in[11];
    const int* ei    = (const int*)d_in[12];
    const int* batch = (const int*)d_in[13];
    float* out = (float*)d_out;
    (void)in_sizes; (void)n_in; (void)out_size; (void)ws_size;

    char* p = (char*)d_ws;
    auto alloc = [&](size_t bytes) -> char* {
        char* r = p;
        p += (bytes + 255) & ~(size_t)255;
        return r;
    };
    u64*   deg_cnt = (u64*)alloc((size_t)NNODES * 8);
    float* dinv   = (float*)alloc((size_t)NNODES * 4);
    unsigned* edges = (unsigned*)alloc((size_t)NNODES * DCAP * 4);  // padded CSR, 12.8 MB
    int*   gp     = (int*)  alloc((size_t)NGRAPH * 512 * 4);
    unsigned short* f1   = (unsigned short*)alloc((size_t)NGRAPH * 1024 * 2);
    unsigned short* wt1  = (unsigned short*)alloc((size_t)128 * 128 * 2);
    unsigned short* wt2  = (unsigned short*)alloc((size_t)256 * 128 * 2);
    unsigned short* wt3  = (unsigned short*)alloc((size_t)512 * 256 * 2);
    unsigned short* wtf1 = (unsigned short*)alloc((size_t)1024 * 512 * 2);
    unsigned short* wtf2 = (unsigned short*)alloc((size_t)128 * 1024 * 2);
    unsigned short* bufA = (unsigned short*)alloc((size_t)NPAD * 256 * 2);
    unsigned short* bufB = (unsigned short*)alloc((size_t)NPAD * 256 * 2);
    unsigned short* x16  = bufB;   // consumed by agg-1 before gemm-1 overwrites bufB
    // total ~68 MB

    const int MB128 = (NNODES + 127) / 128; // 391
    const int AGG = (NNODES + 3) / 4;       // 12500
    const int CVB = (NNODES * 16 + 255) / 256;  // 3125 cvt blocks

    // preprocessing: 1 memset + fused k_pre (edges + transposes + x-cvt) + k_prep
    hipMemsetAsync(deg_cnt, 0, (size_t)NNODES * 8, stream);
    k_pre<<<EBLK + 204 + CVB, 256, 0, stream>>>(W1, W2, W3, Wf1, Wf2,
                                                wt1, wt2, wt3, wtf1, wtf2,
                                                (const int4*)ei, (const int4*)(ei + NEDGES),
                                                (const float4*)ew, deg_cnt, edges, x, x16);
    k_prep<<<1024, 256, 0, stream>>>(deg_cnt, dinv, gp);

    // layer 1 (unscaled x16 -> DSRC aggregate applies dinv[src] per edge)
    k_aggregate<128, 1, true><<<AGG, 256, 0, stream>>>(x16, deg_cnt, edges, dinv, bufA);
    k_gemm128<0><<<dim3(1, MB128), 256, 0, stream>>>(bufA, wt1, b1, bufB, nullptr, nullptr, dinv, NNODES, 128, 128);
    // layer 2
    k_aggregate<128, 1, false><<<AGG, 256, 0, stream>>>(bufB, deg_cnt, edges, dinv, bufA);
    k_gemm128<0><<<dim3(2, MB128), 256, 0, stream>>>(bufA, wt2, b2, bufB, nullptr, nullptr, dinv, NNODES, 256, 128);
    // layer 3 + fused pool (unscaled relu feeds the pool); feature-sliced aggregate (S=2)
    k_aggregate<256, 2, false><<<AGG * 2, 256, 0, stream>>>(bufB, deg_cnt, edges, dinv, bufA);
    k_gemm128<2><<<dim3(4, MB128), 256, 0, stream>>>(bufA, wt3, b3, nullptr, batch, gp, nullptr, NNODES, 512, 256);

    // MLP head (legacy kernel, M=512)
    k_gemm_mfma<0, 1><<<dim3(8, NGRAPH / 64), 256, 0, stream>>>(gp, wtf1, bf1, f1, NGRAPH, 1024, 512);
    k_gemm_mfma<1, 0><<<dim3(1, NGRAPH / 64), 256, 0, stream>>>(f1, wtf2, bf2, out, NGRAPH, 128, 1024);
}

// Round 11
// 361.186 us; speedup vs baseline: 1.0437x; 1.0103x over previous
//
#include <hip/hip_runtime.h>

#define NNODES 50000
#define NPAD   50048   // 391 * 128; padded row count so 128-tile GEMM staging never faults
#define NEDGES 800000
#define NGRAPH 512
#define DCAP 64   // padded edge slots per node; Poisson(16) max ~37, P(>=64) ~ 1e-23

typedef short bf16x8 __attribute__((ext_vector_type(8)));
typedef unsigned short u16x8 __attribute__((ext_vector_type(8)));
typedef float f32x4 __attribute__((ext_vector_type(4)));
typedef unsigned long long u64;

// async global->LDS, 16B per lane (dest = wave-uniform base + lane*16, linear layout)
#define GLOAD16(g, l)                                                                 \
    __builtin_amdgcn_global_load_lds((const __attribute__((address_space(1))) unsigned*)(g), \
                                     (__attribute__((address_space(3))) unsigned*)(l), 16, 0, 0)

// ---------- bf16 <-> fp32 helpers ----------
static __device__ __forceinline__ float b2f(unsigned short u) {
    return __uint_as_float(((unsigned)u) << 16);
}
static __device__ __forceinline__ unsigned short f2b(float f) {
    unsigned u = __float_as_uint(f);
    unsigned r = (u + 0x7fffu + ((u >> 16) & 1u)) >> 16;  // round-nearest-even
    return (unsigned short)r;
}

// accumulate 8 bf16 (packed in uint4) * c into acc[8]
static __device__ __forceinline__ void accum8(float (&acc)[8], float c, uint4 v) {
    unsigned w[4] = {v.x, v.y, v.z, v.w};
    #pragma unroll
    for (int i = 0; i < 4; ++i) {
        acc[2 * i]     += c * __uint_as_float(w[i] << 16);
        acc[2 * i + 1] += c * __uint_as_float(w[i] & 0xffff0000u);
    }
}

// ---------- fused preprocessing under the atomic wall ----------
// Edge placement is memory-side atomic/scatter-store-bound (~57us, all pipes idle).
// Riding under it, for free: (a) W2/W3/Wf1/Wf2 transposes, (b) the ENTIRE layer-1 GEMM
// P1 = X @ W1 (valid because A_hat(XW1) = (A_hat X)W1 and X,W1 are inputs at t=0; the
// reference computes x@W before scattering too). W1 is transposed on-the-fly into LDS
// per GEMM block (WT1 unavailable in-kernel; W1 is 64KB, L2-hot). gemm1 dispatch dies.
#define EBLK 782   // ceil(200000/256) edge blocks (4 edges/thread)
#define TBLK 200   // transpose tiles: W2 8, W3 32, Wf1 128, Wf2 32
#define GBLK 782   // P1-GEMM blocks (64 rows each, covers NPAD)
__global__ __launch_bounds__(256) void k_pre(const float* __restrict__ W1, const float* __restrict__ W2,
                                             const float* __restrict__ W3, const float* __restrict__ Wf1,
                                             const float* __restrict__ Wf2,
                                             unsigned short* __restrict__ T2,
                                             unsigned short* __restrict__ T3, unsigned short* __restrict__ Tf1,
                                             unsigned short* __restrict__ Tf2,
                                             const int4* __restrict__ ei_s, const int4* __restrict__ ei_d,
                                             const float4* __restrict__ ew4,
                                             u64* deg_cnt, unsigned* __restrict__ edges,
                                             const float* __restrict__ x, unsigned short* __restrict__ P1) {
    __shared__ __align__(16) char smem[38912];   // max(transpose 16.6KB, gemm 33.8+5.1KB)
    const int b = blockIdx.x;
    const int tid = threadIdx.x;
    if (b < EBLK) {
        // edge placement: u64 atomic returns old count = this edge's slot; 4 chains/thread
        int t = b * 256 + tid;
        if (t >= NEDGES / 4) return;
        int4 ss = ei_s[t];
        int4 dd = ei_d[t];
        float4 ww = ew4[t];
        int s[4] = {ss.x, ss.y, ss.z, ss.w};
        int d[4] = {dd.x, dd.y, dd.z, dd.w};
        float w[4] = {ww.x, ww.y, ww.z, ww.w};
        int slot[4];
        #pragma unroll
        for (int u = 0; u < 4; ++u) {
            unsigned fixed = __float2uint_rn(w[u] * 16777216.0f);  // 8.24 fixed; ew in [0,1)
            u64 old = atomicAdd(&deg_cnt[d[u]], ((u64)1 << 32) | fixed);
            slot[u] = (int)(old >> 32);
            if (slot[u] > DCAP - 1) slot[u] = DCAP - 1;  // never fires (safety)
        }
        #pragma unroll
        for (int u = 0; u < 4; ++u)
            edges[((unsigned)d[u] << 6) | slot[u]] = ((unsigned)f2b(w[u]) << 16) | (unsigned)s[u];
        return;
    }
    if (b < EBLK + TBLK) {
        // W[K][N] fp32 -> WT[N][K] bf16, 64x64 LDS tile, both global sides coalesced
        const int bb = b - EBLK;
        const float* W; unsigned short* T; int K, N, t0;
        if (bb < 8)        { W = W2;  T = T2;  K = 128;  N = 256;  t0 = 0;   }
        else if (bb < 40)  { W = W3;  T = T3;  K = 256;  N = 512;  t0 = 8;   }
        else if (bb < 168) { W = Wf1; T = Tf1; K = 512;  N = 1024; t0 = 40;  }
        else               { W = Wf2; T = Tf2; K = 1024; N = 128;  t0 = 168; }
        const int tile = bb - t0;
        const int ntn = N >> 6;
        const int k0 = (tile / ntn) * 64, n0 = (tile % ntn) * 64;
        float (*sm)[65] = (float(*)[65])smem;
        const int rr = tid >> 6, cc = tid & 63;
        #pragma unroll
        for (int r = 0; r < 16; ++r) {
            int kl = r * 4 + rr;
            sm[kl][cc] = W[(size_t)(k0 + kl) * N + n0 + cc];
        }
        __syncthreads();
        #pragma unroll
        for (int r = 0; r < 16; ++r) {
            int nl = r * 4 + rr;
            T[(size_t)(n0 + nl) * K + k0 + cc] = f2b(sm[cc][nl]);
        }
        return;
    }
    // ---- P1 = X @ W1 (64x128 tile per block, K=128), B transposed on-the-fly ----
    const int gb = b - EBLK - TBLK;          // 0..781
    const int m0 = gb * 64;
    unsigned short* BsT = (unsigned short*)smem;             // [128][132] bf16, W1^T
    unsigned short* As  = (unsigned short*)(smem + 33792);   // [64][40] bf16
    const float4* W1v = (const float4*)W1;   // 128x128 f32 = 4096 float4
    #pragma unroll
    for (int i = 0; i < 16; ++i) {
        int idx = i * 256 + tid;             // 0..4095
        int k = idx >> 5, q = idx & 31;      // row k, col-quad q
        float4 v = W1v[idx];
        int n = q * 4;
        BsT[(n + 0) * 132 + k] = f2b(v.x);
        BsT[(n + 1) * 132 + k] = f2b(v.y);
        BsT[(n + 2) * 132 + k] = f2b(v.z);
        BsT[(n + 3) * 132 + k] = f2b(v.w);
    }
    const int wave = tid >> 6, lane = tid & 63;
    const int wm = (wave >> 1) * 32, wn = (wave & 1) * 64;
    const int quad = lane >> 4, mrow = lane & 15;
    const int ar = tid >> 2, ak = (tid & 3) * 8;
    const bool arow_ok = (m0 + ar) < NNODES;   // x is exactly 50000 rows (input)
    f32x4 acc[2][4] = {};
    __syncthreads();
    for (int k0 = 0; k0 < 128; k0 += 32) {
        u16x8 av = {};
        if (arow_ok) {
            const float* Af = x + (size_t)(m0 + ar) * 128 + k0 + ak;
            float4 f0 = *(const float4*)Af;
            float4 f1 = *(const float4*)(Af + 4);
            av[0] = (short)f2b(f0.x); av[1] = (short)f2b(f0.y);
            av[2] = (short)f2b(f0.z); av[3] = (short)f2b(f0.w);
            av[4] = (short)f2b(f1.x); av[5] = (short)f2b(f1.y);
            av[6] = (short)f2b(f1.z); av[7] = (short)f2b(f1.w);
        }
        *(u16x8*)&As[ar * 40 + ak] = av;
        __syncthreads();
        bf16x8 af[2], bf[4];
        #pragma unroll
        for (int mt = 0; mt < 2; ++mt)
            af[mt] = *(const bf16x8*)&As[(wm + mt * 16 + mrow) * 40 + quad * 8];
        #pragma unroll
        for (int nt = 0; nt < 4; ++nt)
            bf[nt] = *(const bf16x8*)&BsT[(wn + nt * 16 + mrow) * 132 + k0 + quad * 8];
        #pragma unroll
        for (int mt = 0; mt < 2; ++mt)
            #pragma unroll
            for (int nt = 0; nt < 4; ++nt)
                acc[mt][nt] = __builtin_amdgcn_mfma_f32_16x16x32_bf16(af[mt], bf[nt], acc[mt][nt], 0, 0, 0);
        __syncthreads();
    }
    // store P1 (bf16, rows < NPAD guaranteed; garbage rows beyond NNODES are never read)
    #pragma unroll
    for (int mt = 0; mt < 2; ++mt)
        #pragma unroll
        for (int r = 0; r < 4; ++r) {
            int row = m0 + wm + mt * 16 + quad * 4 + r;
            #pragma unroll
            for (int nt = 0; nt < 4; ++nt)
                P1[(size_t)row * 128 + wn + nt * 16 + mrow] = f2b(acc[mt][nt][r]);
        }
}

// dinv from packed degree (+1.0 self-loop folded in) + gp zero
__global__ void k_prep(const u64* __restrict__ deg_cnt, float* __restrict__ dinv, int* __restrict__ gp) {
    int i = blockIdx.x * 256 + threadIdx.x;
    if (i < NNODES)
        dinv[i] = rsqrtf((float)(unsigned)(deg_cnt[i] & 0xffffffffull) * 5.9604645e-8f + 1.0f);
    if (i < NGRAPH * 512) gp[i] = 0;   // +0.0f bits; relu pool >= 0
}

// ---------- aggregation: Z[d,:] = epi( dinv[d] * (self + sum_e c_e * X[src_e,:]) ) ----------
// wave-per-(node, feature-slice). SLICES=2 (F=256): slice parity == XCD parity under
// round-robin dispatch -> 12.8MB half-table per XCD L2 (r8: FETCH 187->162MB).
// DSRC: X unscaled -> c_e = w_e * dinv[src] (pipelined broadcast load); self scaled di.
// EPI: fused layer-1 epilogue out = dinv * relu(z + bias) (replaces gemm1's epilogue).
// 16B dwordx4 gathers, rotating 2-deep pipeline, weight-0 masked tail,
// cross-group shfl reduce, 16B stores by group 0.
template <int F, int SLICES, bool DSRC, bool EPI>
__global__ __launch_bounds__(256) void k_aggregate(const unsigned short* __restrict__ X,
                                                   const u64* __restrict__ deg_cnt,
                                                   const unsigned* __restrict__ edges,
                                                   const float* __restrict__ dinv,
                                                   unsigned short* __restrict__ Z,
                                                   const float* __restrict__ bias) {
    constexpr int FS = F / SLICES;     // features handled per block
    constexpr int LPR = FS / 8;        // lanes per source row-slice (16 or 32)
    constexpr int GRP = 64 / LPR;      // edges per step (4 or 2)
    constexpr int STEP = GRP * 2;      // edges per pair-iteration (8 or 4)
    const int bid = blockIdx.x;
    const int slice = (SLICES == 1) ? 0 : (bid & (SLICES - 1));
    const int chunk = (SLICES == 1) ? bid : (bid / SLICES);
    const int wave = threadIdx.x >> 6, lane = threadIdx.x & 63;
    const int node = chunk * 4 + wave;
    if (node >= NNODES) return;
    const int sub = lane & (LPR - 1);
    const int grp = lane / LPR;
    const int fo = slice * FS + sub * 8;
    const unsigned short* Xf = X + fo;
    const float di = dinv[node];
    const int cnt = (int)(deg_cnt[node] >> 32);
    const unsigned* erow = edges + ((unsigned)node << 6);

    // self row-slice: issue early, consumed in epilogue
    const uint4 selfv = *(const uint4*)(Xf + (size_t)node * F);

    float acc[8] = {};

    const int e0 = grp;
    const int nb = (cnt + STEP - 1) / STEP;   // pair-iterations (wave-uniform)

    unsigned pa0 = 0, pb0 = 0, pa1 = 0, pb1 = 0;
    uint4 va0 = {}, vb0 = {};
    float da0 = 1.f, db0 = 1.f;
    if (nb > 0) {
        int ea = e0, eb = e0 + GRP;
        pa0 = (ea < cnt) ? erow[ea] : 0u;
        pb0 = (eb < cnt) ? erow[eb] : 0u;
        va0 = *(const uint4*)(Xf + (size_t)(pa0 & 0xffffu) * F);
        vb0 = *(const uint4*)(Xf + (size_t)(pb0 & 0xffffu) * F);
        if constexpr (DSRC) { da0 = dinv[pa0 & 0xffffu]; db0 = dinv[pb0 & 0xffffu]; }
        if (nb > 1) {
            int ea1 = e0 + STEP, eb1 = ea1 + GRP;
            pa1 = (ea1 < cnt) ? erow[ea1] : 0u;
            pb1 = (eb1 < cnt) ? erow[eb1] : 0u;
        }
    }
    for (int p = 0; p < nb; ++p) {
        uint4 va1 = {}, vb1 = {};
        float da1 = 1.f, db1 = 1.f;
        unsigned pa2 = 0, pb2 = 0;
        if (p + 1 < nb) {
            va1 = *(const uint4*)(Xf + (size_t)(pa1 & 0xffffu) * F);
            vb1 = *(const uint4*)(Xf + (size_t)(pb1 & 0xffffu) * F);
            if constexpr (DSRC) { da1 = dinv[pa1 & 0xffffu]; db1 = dinv[pb1 & 0xffffu]; }
            if (p + 2 < nb) {
                int ea = e0 + (p + 2) * STEP, eb = ea + GRP;
                pa2 = (ea < cnt) ? erow[ea] : 0u;
                pb2 = (eb < cnt) ? erow[eb] : 0u;
            }
        }
        float ca = b2f((unsigned short)(pa0 >> 16));
        float cb = b2f((unsigned short)(pb0 >> 16));
        if constexpr (DSRC) { ca *= da0; cb *= db0; }
        accum8(acc, ca, va0);
        accum8(acc, cb, vb0);
        pa0 = pa1; pb0 = pb1; va0 = va1; vb0 = vb1;
        da0 = da1; db0 = db1;
        pa1 = pa2; pb1 = pb2;
    }

    // cross-group reduce
    #pragma unroll
    for (int j = 0; j < 8; ++j) {
        if constexpr (GRP == 4) acc[j] += __shfl_xor(acc[j], 16, 64);
        acc[j] += __shfl_xor(acc[j], 32, 64);
    }

    if (grp == 0) {
        float bv[8];
        if constexpr (EPI) {
            float4 q0 = *(const float4*)(bias + fo);
            float4 q1 = *(const float4*)(bias + fo + 4);
            bv[0] = q0.x; bv[1] = q0.y; bv[2] = q0.z; bv[3] = q0.w;
            bv[4] = q1.x; bv[5] = q1.y; bv[6] = q1.z; bv[7] = q1.w;
        }
        const float sc = DSRC ? di : 1.0f;   // self term scale (unscaled X path)
        unsigned w[4] = {selfv.x, selfv.y, selfv.z, selfv.w};
        unsigned o[4];
        #pragma unroll
        for (int i = 0; i < 4; ++i) {
            float s0 = __uint_as_float(w[i] << 16);
            float s1 = __uint_as_float(w[i] & 0xffff0000u);
            float z0 = di * (acc[2 * i] + sc * s0);
            float z1 = di * (acc[2 * i + 1] + sc * s1);
            if constexpr (EPI) {
                z0 = di * fmaxf(z0 + bv[2 * i], 0.f);
                z1 = di * fmaxf(z1 + bv[2 * i + 1], 0.f);
            }
            o[i] = (unsigned)f2b(z0) | ((unsigned)f2b(z1) << 16);
        }
        uint4 ov; ov.x = o[0]; ov.y = o[1]; ov.z = o[2]; ov.w = o[3];
        *(uint4*)(Z + (size_t)node * F + fo) = ov;
    }
}

// ---------- m97-structure GEMM, 2-phase double-buffered (T3-minimum) ----------
// 128x128 tile, 4 waves (2x2), each 64x64 = 4x4 16x16x32 fragments. BK=32.
// Double-buffered linear LDS [2][128][32]; next tile's global_load_lds issued BEFORE
// current tile's ds_read+MFMA; one vmcnt-drain barrier/tile. NPAD covers staging OOB
// (garbage rows only affect their own guarded outputs — MFMA rows are independent).
// Bijective XCD chunking (m204): each XCD owns a contiguous m-range for all n-blocks.
// CMODE 0: bf16 store + relu + optional rscale. 2: fused per-graph relu+max-pool.
template <int CMODE>
__global__ __launch_bounds__(256) void k_gemm128(const unsigned short* __restrict__ A,
                                                 const unsigned short* __restrict__ WT,
                                                 const float* __restrict__ bias,
                                                 unsigned short* __restrict__ C,
                                                 const int* __restrict__ batch,
                                                 int* __restrict__ gp,
                                                 const float* __restrict__ rscale,
                                                 int M, int N, int K) {
    __shared__ unsigned short As[2][128 * 32];
    __shared__ unsigned short Bs[2][128 * 32];
    const int tid = threadIdx.x;

    // bijective XCD remap of flat block id (xcd = f % 8 under round-robin dispatch)
    const int nwg = gridDim.x * gridDim.y;
    const int f = blockIdx.y * gridDim.x + blockIdx.x;
    const int q = nwg >> 3, r = nwg & 7;
    const int xcd = f & 7, idx = f >> 3;
    const int w = (xcd < r) ? xcd * (q + 1) + idx : r * (q + 1) + (xcd - r) * q + idx;
    const int m0 = (w / gridDim.x) * 128;
    const int n0 = (w % gridDim.x) * 128;

    const int wave = tid >> 6, lane = tid & 63;
    const int wm = (wave >> 1) * 64, wn = (wave & 1) * 64;
    const int quad = lane >> 4, mrow = lane & 15;

    const int sr = tid >> 2;              // staging row 0..63
    const int sc = (tid & 3) * 8;         // staging col (shorts)
    const unsigned short* Ag0 = A + (size_t)(m0 + sr) * K + sc;
    const unsigned short* Ag1 = A + (size_t)(m0 + 64 + sr) * K + sc;
    const unsigned short* Bg0 = WT + (size_t)(n0 + sr) * K + sc;
    const unsigned short* Bg1 = WT + (size_t)(n0 + 64 + sr) * K + sc;
    const int so0 = sr * 32 + sc, so1 = (64 + sr) * 32 + sc;

    f32x4 acc[4][4] = {};
    const int nsteps = K >> 5;

    // prologue: stage tile 0 into buffer 0
    GLOAD16(Ag0, &As[0][so0]);
    GLOAD16(Ag1, &As[0][so1]);
    GLOAD16(Bg0, &Bs[0][so0]);
    GLOAD16(Bg1, &Bs[0][so1]);
    __syncthreads();   // vmcnt(0) drain + barrier

    for (int step = 0; step < nsteps; ++step) {
        const int cur = step & 1;
        if (step + 1 < nsteps) {           // issue next tile while computing current
            const int k1 = (step + 1) << 5;
            GLOAD16(Ag0 + k1, &As[cur ^ 1][so0]);
            GLOAD16(Ag1 + k1, &As[cur ^ 1][so1]);
            GLOAD16(Bg0 + k1, &Bs[cur ^ 1][so0]);
            GLOAD16(Bg1 + k1, &Bs[cur ^ 1][so1]);
        }
        bf16x8 af[4], bf[4];
        #pragma unroll
        for (int mt = 0; mt < 4; ++mt)
            af[mt] = *(const bf16x8*)&As[cur][(wm + mt * 16 + mrow) * 32 + quad * 8];
        #pragma unroll
        for (int nt = 0; nt < 4; ++nt)
            bf[nt] = *(const bf16x8*)&Bs[cur][(wn + nt * 16 + mrow) * 32 + quad * 8];
        #pragma unroll
        for (int mt = 0; mt < 4; ++mt)
            #pragma unroll
            for (int nt = 0; nt < 4; ++nt)
                acc[mt][nt] = __builtin_amdgcn_mfma_f32_16x16x32_bf16(af[mt], bf[nt], acc[mt][nt], 0, 0, 0);
        __syncthreads();   // drains prefetch vmcnt + this tile's lgkm; gates buffer reuse
    }

    float bn[4];
    #pragma unroll
    for (int nt = 0; nt < 4; ++nt) bn[nt] = bias[n0 + wn + nt * 16 + mrow];

    if constexpr (CMODE == 0) {
        #pragma unroll
        for (int mt = 0; mt < 4; ++mt) {
            #pragma unroll
            for (int r4 = 0; r4 < 4; ++r4) {
                int row = m0 + wm + mt * 16 + quad * 4 + r4;
                if (row < M) {
                    float rs = rscale ? rscale[row] : 1.0f;
                    #pragma unroll
                    for (int nt = 0; nt < 4; ++nt) {
                        float v = fmaxf(acc[mt][nt][r4] + bn[nt], 0.f) * rs;
                        C[(size_t)row * N + n0 + wn + nt * 16 + mrow] = f2b(v);
                    }
                }
            }
        }
    } else {
        // per-wave pool: wave covers 64 rows -> spans <=2 graphs (min graph size 97)
        const int wr0 = m0 + wm;
        int g0i = wr0 < M ? wr0 : M - 1;
        const int g0 = batch[g0i];
        int lastr = wr0 + 63; if (lastr >= M) lastr = M - 1;
        const int gl = batch[lastr];
        bool rok[16]; int gid[16];
        #pragma unroll
        for (int mt = 0; mt < 4; ++mt)
            #pragma unroll
            for (int r4 = 0; r4 < 4; ++r4) {
                int row = wr0 + mt * 16 + quad * 4 + r4;
                rok[mt * 4 + r4] = row < M;
                gid[mt * 4 + r4] = (row < M) ? batch[row] : -1;
            }
        #pragma unroll
        for (int nt = 0; nt < 4; ++nt) {
            float v0 = 0.f, v1 = 0.f;
            #pragma unroll
            for (int mt = 0; mt < 4; ++mt)
                #pragma unroll
                for (int r4 = 0; r4 < 4; ++r4)
                    if (rok[mt * 4 + r4]) {
                        float v = fmaxf(acc[mt][nt][r4] + bn[nt], 0.f);
                        if (gid[mt * 4 + r4] == g0) v0 = fmaxf(v0, v);
                        else v1 = fmaxf(v1, v);
                    }
            v0 = fmaxf(v0, __shfl_xor(v0, 16, 64));
            v0 = fmaxf(v0, __shfl_xor(v0, 32, 64));
            v1 = fmaxf(v1, __shfl_xor(v1, 16, 64));
            v1 = fmaxf(v1, __shfl_xor(v1, 32, 64));
            if (quad == 0) {
                int c = n0 + wn + nt * 16 + mrow;
                atomicMax(&gp[(size_t)g0 * N + c], __float_as_int(v0));
                if (gl != g0) atomicMax(&gp[(size_t)gl * N + c], __float_as_int(v1));
            }
        }
    }
}

// ---------- legacy GEMM for the small MLP head (M=512) ----------
// block 64(M) x 128(N), 4 waves (2x2 of 32x64), BK=32, 16x16x32 MFMA.
// CMODE 0: bf16 store + relu. 1: fp32 store, no relu. AFP: A is fp32.
template <int CMODE, int AFP>
__global__ __launch_bounds__(256) void k_gemm_mfma(const void* __restrict__ Av,
                                                   const unsigned short* __restrict__ WT,
                                                   const float* __restrict__ bias,
                                                   void* __restrict__ Cv,
                                                   int M, int N, int K) {
    constexpr int LDK = 40;
    __shared__ unsigned short As[64 * LDK];
    __shared__ unsigned short Bs[128 * LDK];
    const int tid = threadIdx.x;
    const int m0 = blockIdx.y * 64, n0 = blockIdx.x * 128;
    const int wave = tid >> 6, lane = tid & 63;
    const int wm = (wave >> 1) * 32;
    const int wn = (wave & 1) * 64;
    const int quad = lane >> 4, mrow = lane & 15;

    const int ar = tid >> 2;
    const int ak = (tid & 3) * 8;
    const bool arow_ok = (m0 + ar) < M;
    const size_t aoff = (size_t)(m0 + ar) * K + ak;
    const unsigned short* Bg0 = WT + (size_t)(n0 + ar) * K + ak;
    const unsigned short* Bg1 = WT + (size_t)(n0 + ar + 64) * K + ak;

    f32x4 acc[2][4] = {};

    for (int k0 = 0; k0 < K; k0 += 32) {
        u16x8 av = {};
        if (arow_ok) {
            if constexpr (AFP) {
                const float* Af = (const float*)Av + aoff + k0;
                float4 f0 = *(const float4*)Af;
                float4 f1 = *(const float4*)(Af + 4);
                av[0] = (short)f2b(f0.x); av[1] = (short)f2b(f0.y);
                av[2] = (short)f2b(f0.z); av[3] = (short)f2b(f0.w);
                av[4] = (short)f2b(f1.x); av[5] = (short)f2b(f1.y);
                av[6] = (short)f2b(f1.z); av[7] = (short)f2b(f1.w);
            } else {
                av = *(const u16x8*)((const unsigned short*)Av + aoff + k0);
            }
        }
        u16x8 bv0 = *(const u16x8*)(Bg0 + k0);
        u16x8 bv1 = *(const u16x8*)(Bg1 + k0);
        *(u16x8*)&As[ar * LDK + ak] = av;
        *(u16x8*)&Bs[ar * LDK + ak] = bv0;
        *(u16x8*)&Bs[(ar + 64) * LDK + ak] = bv1;
        __syncthreads();
        bf16x8 af[2], bf[4];
        #pragma unroll
        for (int mt = 0; mt < 2; ++mt)
            af[mt] = *(const bf16x8*)&As[(wm + mt * 16 + mrow) * LDK + quad * 8];
        #pragma unroll
        for (int nt = 0; nt < 4; ++nt)
            bf[nt] = *(const bf16x8*)&Bs[(wn + nt * 16 + mrow) * LDK + quad * 8];
        #pragma unroll
        for (int mt = 0; mt < 2; ++mt)
            #pragma unroll
            for (int nt = 0; nt < 4; ++nt)
                acc[mt][nt] = __builtin_amdgcn_mfma_f32_16x16x32_bf16(af[mt], bf[nt], acc[mt][nt], 0, 0, 0);
        __syncthreads();
    }

    float bn[4];
    #pragma unroll
    for (int nt = 0; nt < 4; ++nt) bn[nt] = bias[n0 + wn + nt * 16 + mrow];

    if constexpr (CMODE == 0) {
        unsigned short* C = (unsigned short*)Cv;
        #pragma unroll
        for (int mt = 0; mt < 2; ++mt) {
            #pragma unroll
            for (int r = 0; r < 4; ++r) {
                int row = m0 + wm + mt * 16 + quad * 4 + r;
                if (row < M) {
                    #pragma unroll
                    for (int nt = 0; nt < 4; ++nt) {
                        float v = fmaxf(acc[mt][nt][r] + bn[nt], 0.f);
                        C[(size_t)row * N + n0 + wn + nt * 16 + mrow] = f2b(v);
                    }
                }
            }
        }
    } else {
        float* C = (float*)Cv;
        #pragma unroll
        for (int mt = 0; mt < 2; ++mt) {
            #pragma unroll
            for (int r = 0; r < 4; ++r) {
                int row = m0 + wm + mt * 16 + quad * 4 + r;
                if (row < M) {
                    #pragma unroll
                    for (int nt = 0; nt < 4; ++nt)
                        C[(size_t)row * N + n0 + wn + nt * 16 + mrow] = acc[mt][nt][r] + bn[nt];
                }
            }
        }
    }
}

extern "C" void kernel_launch(void* const* d_in, const int* in_sizes, int n_in,
                              void* d_out, int out_size, void* d_ws, size_t ws_size,
                              hipStream_t stream) {
    const float* x   = (const float*)d_in[0];
    const float* ew  = (const float*)d_in[1];
    const float* W1  = (const float*)d_in[2];
    const float* b1  = (const float*)d_in[3];
    const float* W2  = (const float*)d_in[4];
    const float* b2  = (const float*)d_in[5];
    const float* W3  = (const float*)d_in[6];
    const float* b3  = (const float*)d_in[7];
    const float* Wf1 = (const float*)d_in[8];
    const float* bf1 = (const float*)d_in[9];
    const float* Wf2 = (const float*)d_in[10];
    const float* bf2 = (const float*)d_in[11];
    const int* ei    = (const int*)d_in[12];
    const int* batch = (const int*)d_in[13];
    float* out = (float*)d_out;
    (void)in_sizes; (void)n_in; (void)out_size; (void)ws_size;

    char* p = (char*)d_ws;
    auto alloc = [&](size_t bytes) -> char* {
        char* r = p;
        p += (bytes + 255) & ~(size_t)255;
        return r;
    };
    u64*   deg_cnt = (u64*)alloc((size_t)NNODES * 8);
    float* dinv   = (float*)alloc((size_t)NNODES * 4);
    unsigned* edges = (unsigned*)alloc((size_t)NNODES * DCAP * 4);  // padded CSR, 12.8 MB
    int*   gp     = (int*)  alloc((size_t)NGRAPH * 512 * 4);
    unsigned short* f1   = (unsigned short*)alloc((size_t)NGRAPH * 1024 * 2);
    unsigned short* wt2  = (unsigned short*)alloc((size_t)256 * 128 * 2);
    unsigned short* wt3  = (unsigned short*)alloc((size_t)512 * 256 * 2);
    unsigned short* wtf1 = (unsigned short*)alloc((size_t)1024 * 512 * 2);
    unsigned short* wtf2 = (unsigned short*)alloc((size_t)128 * 1024 * 2);
    unsigned short* bufA = (unsigned short*)alloc((size_t)NPAD * 256 * 2);
    unsigned short* bufB = (unsigned short*)alloc((size_t)NPAD * 256 * 2);
    unsigned short* P1   = bufB;   // layer-1 pre-GEMM result (consumed by agg1)
    // total ~68 MB

    const int MB128 = (NNODES + 127) / 128; // 391
    const int AGG = (NNODES + 3) / 4;       // 12500

    // preprocessing: memset + fused k_pre (edges + transposes + P1 GEMM) + k_prep
    hipMemsetAsync(deg_cnt, 0, (size_t)NNODES * 8, stream);
    k_pre<<<EBLK + TBLK + GBLK, 256, 0, stream>>>(W1, W2, W3, Wf1, Wf2,
                                                  wt2, wt3, wtf1, wtf2,
                                                  (const int4*)ei, (const int4*)(ei + NEDGES),
                                                  (const float4*)ew, deg_cnt, edges, x, P1);
    k_prep<<<1024, 256, 0, stream>>>(deg_cnt, dinv, gp);

    // layer 1: H1' = dinv * relu( A_hat @ P1 + b1 )  — gemm1 eliminated (P1 under the wall)
    k_aggregate<128, 1, true, true><<<AGG, 256, 0, stream>>>(P1, deg_cnt, edges, dinv, bufA, b1);
    // layer 2
    k_aggregate<128, 1, false, false><<<AGG, 256, 0, stream>>>(bufA, deg_cnt, edges, dinv, bufB, nullptr);
    k_gemm128<0><<<dim3(2, MB128), 256, 0, stream>>>(bufB, wt2, b2, bufA, nullptr, nullptr, dinv, NNODES, 256, 128);
    // layer 3 + fused pool (unscaled relu feeds the pool); feature-sliced aggregate (S=2)
    k_aggregate<256, 2, false, false><<<AGG * 2, 256, 0, stream>>>(bufA, deg_cnt, edges, dinv, bufB, nullptr);
    k_gemm128<2><<<dim3(4, MB128), 256, 0, stream>>>(bufB, wt3, b3, nullptr, batch, gp, nullptr, NNODES, 512, 256);

    // MLP head (legacy kernel, M=512)
    k_gemm_mfma<0, 1><<<dim3(8, NGRAPH / 64), 256, 0, stream>>>(gp, wtf1, bf1, f1, NGRAPH, 1024, 512);
    k_gemm_mfma<1, 0><<<dim3(1, NGRAPH / 64), 256, 0, stream>>>(f1, wtf2, bf2, out, NGRAPH, 128, 1024);
}

// Round 12
// 356.944 us; speedup vs baseline: 1.0561x; 1.0119x over previous
//
#include <hip/hip_runtime.h>

#define NNODES 50000
#define NPAD   50048   // 391 * 128; padded row count so 128-tile GEMM staging never faults
#define NEDGES 800000
#define NGRAPH 512
#define DCAP 64   // padded edge slots per node; Poisson(16) max ~37, P(>=64) ~ 1e-23

typedef short bf16x8 __attribute__((ext_vector_type(8)));
typedef unsigned short u16x8 __attribute__((ext_vector_type(8)));
typedef float f32x4 __attribute__((ext_vector_type(4)));
typedef unsigned long long u64;

// async global->LDS, 16B per lane (dest = wave-uniform base + lane*16, linear layout)
#define GLOAD16(g, l)                                                                 \
    __builtin_amdgcn_global_load_lds((const __attribute__((address_space(1))) unsigned*)(g), \
                                     (__attribute__((address_space(3))) unsigned*)(l), 16, 0, 0)

// ---------- bf16 <-> fp32 helpers ----------
static __device__ __forceinline__ float b2f(unsigned short u) {
    return __uint_as_float(((unsigned)u) << 16);
}
static __device__ __forceinline__ unsigned short f2b(float f) {
    unsigned u = __float_as_uint(f);
    unsigned r = (u + 0x7fffu + ((u >> 16) & 1u)) >> 16;  // round-nearest-even
    return (unsigned short)r;
}

// accumulate 8 bf16 (packed in uint4) * c into acc[8]
static __device__ __forceinline__ void accum8(float (&acc)[8], float c, uint4 v) {
    unsigned w[4] = {v.x, v.y, v.z, v.w};
    #pragma unroll
    for (int i = 0; i < 4; ++i) {
        acc[2 * i]     += c * __uint_as_float(w[i] << 16);
        acc[2 * i + 1] += c * __uint_as_float(w[i] & 0xffff0000u);
    }
}

// ---------- fused preprocessing under the atomic wall ----------
// Edge placement is memory-side atomic/scatter-store-bound (~57us, all pipes idle).
// Riding under it, for free: (a) the ENTIRE layer-1 GEMM P1 = X @ W1 (valid since
// A_hat(XW1) = (A_hat X)W1; X,W1 are t=0 inputs), (b) W2/W3/Wf1/Wf2 transposes.
// r11 lesson: the GEMM branch must be LDS-FREE — a 33.8KB LDS B-tile collapsed
// occupancy for ALL phases (35%) and its transpose writes were 8-way bank conflicts
// (3.0M). W1 is 64KB L2/L1-hot: build MFMA fragments directly from global (A: 2x
// float4 per lane; B: 8 scalar dwords per fragment, 4x64B coalesced per instr).
#define EBLK 782   // ceil(200000/256) edge blocks (4 edges/thread)
#define GBLK 782   // P1-GEMM blocks (64 rows each, covers NPAD)
#define TBLK 200   // transpose tiles: W2 8, W3 32, Wf1 128, Wf2 32
__global__ __launch_bounds__(256) void k_pre(const float* __restrict__ W1, const float* __restrict__ W2,
                                             const float* __restrict__ W3, const float* __restrict__ Wf1,
                                             const float* __restrict__ Wf2,
                                             unsigned short* __restrict__ T2,
                                             unsigned short* __restrict__ T3, unsigned short* __restrict__ Tf1,
                                             unsigned short* __restrict__ Tf2,
                                             const int4* __restrict__ ei_s, const int4* __restrict__ ei_d,
                                             const float4* __restrict__ ew4,
                                             u64* deg_cnt, unsigned* __restrict__ edges,
                                             const float* __restrict__ x, unsigned short* __restrict__ P1) {
    __shared__ float sm[64][65];   // transpose branch only (16.6KB)
    const int b = blockIdx.x;
    const int tid = threadIdx.x;
    if (b < EBLK) {
        // edge placement: u64 atomic returns old count = this edge's slot; 4 chains/thread
        int t = b * 256 + tid;
        if (t >= NEDGES / 4) return;
        int4 ss = ei_s[t];
        int4 dd = ei_d[t];
        float4 ww = ew4[t];
        int s[4] = {ss.x, ss.y, ss.z, ss.w};
        int d[4] = {dd.x, dd.y, dd.z, dd.w};
        float w[4] = {ww.x, ww.y, ww.z, ww.w};
        int slot[4];
        #pragma unroll
        for (int u = 0; u < 4; ++u) {
            unsigned fixed = __float2uint_rn(w[u] * 16777216.0f);  // 8.24 fixed; ew in [0,1)
            u64 old = atomicAdd(&deg_cnt[d[u]], ((u64)1 << 32) | fixed);
            slot[u] = (int)(old >> 32);
            if (slot[u] > DCAP - 1) slot[u] = DCAP - 1;  // never fires (safety)
        }
        #pragma unroll
        for (int u = 0; u < 4; ++u)
            edges[((unsigned)d[u] << 6) | slot[u]] = ((unsigned)f2b(w[u]) << 16) | (unsigned)s[u];
        return;
    }
    if (b < EBLK + GBLK) {
        // ---- P1 = X @ W1 (64x128 tile, K=128), LDS-free fragments from global ----
        const int gb = b - EBLK;
        const int m0 = gb * 64;
        const int wave = tid >> 6, lane = tid & 63;
        const int wm = (wave >> 1) * 32, wn = (wave & 1) * 64;
        const int quad = lane >> 4, mrow = lane & 15;
        f32x4 acc[2][4] = {};
        #pragma unroll
        for (int ks = 0; ks < 4; ++ks) {
            const int k0 = ks * 32 + quad * 8;
            bf16x8 af[2], bf[4];
            #pragma unroll
            for (int mt = 0; mt < 2; ++mt) {
                int row = m0 + wm + mt * 16 + mrow;
                bf16x8 av = {};
                if (row < NNODES) {
                    const float* Af = x + (size_t)row * 128 + k0;
                    float4 f0 = *(const float4*)Af;
                    float4 f1 = *(const float4*)(Af + 4);
                    av[0] = (short)f2b(f0.x); av[1] = (short)f2b(f0.y);
                    av[2] = (short)f2b(f0.z); av[3] = (short)f2b(f0.w);
                    av[4] = (short)f2b(f1.x); av[5] = (short)f2b(f1.y);
                    av[6] = (short)f2b(f1.z); av[7] = (short)f2b(f1.w);
                }
                af[mt] = av;
            }
            #pragma unroll
            for (int nt = 0; nt < 4; ++nt) {
                int n = wn + nt * 16 + mrow;
                bf16x8 bv;
                #pragma unroll
                for (int j = 0; j < 8; ++j)
                    bv[j] = (short)f2b(W1[(size_t)(k0 + j) * 128 + n]);
                bf[nt] = bv;
            }
            #pragma unroll
            for (int mt = 0; mt < 2; ++mt)
                #pragma unroll
                for (int nt = 0; nt < 4; ++nt)
                    acc[mt][nt] = __builtin_amdgcn_mfma_f32_16x16x32_bf16(af[mt], bf[nt], acc[mt][nt], 0, 0, 0);
        }
        // store P1 (bf16; rows < NPAD by construction; rows >= NNODES never read)
        #pragma unroll
        for (int mt = 0; mt < 2; ++mt)
            #pragma unroll
            for (int r = 0; r < 4; ++r) {
                int row = m0 + wm + mt * 16 + quad * 4 + r;
                #pragma unroll
                for (int nt = 0; nt < 4; ++nt)
                    P1[(size_t)row * 128 + wn + nt * 16 + mrow] = f2b(acc[mt][nt][r]);
            }
        return;
    }
    // ---- W[K][N] fp32 -> WT[N][K] bf16, 64x64 LDS tile, both sides coalesced ----
    const int bb = b - EBLK - GBLK;
    const float* W; unsigned short* T; int K, N, t0;
    if (bb < 8)        { W = W2;  T = T2;  K = 128;  N = 256;  t0 = 0;   }
    else if (bb < 40)  { W = W3;  T = T3;  K = 256;  N = 512;  t0 = 8;   }
    else if (bb < 168) { W = Wf1; T = Tf1; K = 512;  N = 1024; t0 = 40;  }
    else               { W = Wf2; T = Tf2; K = 1024; N = 128;  t0 = 168; }
    const int tile = bb - t0;
    const int ntn = N >> 6;
    const int k0 = (tile / ntn) * 64, n0 = (tile % ntn) * 64;
    const int rr = tid >> 6, cc = tid & 63;
    #pragma unroll
    for (int r = 0; r < 16; ++r) {
        int kl = r * 4 + rr;
        sm[kl][cc] = W[(size_t)(k0 + kl) * N + n0 + cc];
    }
    __syncthreads();
    #pragma unroll
    for (int r = 0; r < 16; ++r) {
        int nl = r * 4 + rr;
        T[(size_t)(n0 + nl) * K + k0 + cc] = f2b(sm[cc][nl]);
    }
}

// dinv from packed degree (+1.0 self-loop folded in) + gp zero
__global__ void k_prep(const u64* __restrict__ deg_cnt, float* __restrict__ dinv, int* __restrict__ gp) {
    int i = blockIdx.x * 256 + threadIdx.x;
    if (i < NNODES)
        dinv[i] = rsqrtf((float)(unsigned)(deg_cnt[i] & 0xffffffffull) * 5.9604645e-8f + 1.0f);
    if (i < NGRAPH * 512) gp[i] = 0;   // +0.0f bits; relu pool >= 0
}

// ---------- aggregation: Z[d,:] = epi( dinv[d] * (self + sum_e c_e * X[src_e,:]) ) ----------
// wave-per-(node, feature-slice). SLICES=2 (F=256): slice parity == XCD parity under
// round-robin dispatch -> 12.8MB half-table per XCD L2 (r8: FETCH 187->162MB).
// DSRC: X unscaled -> c_e = w_e * dinv[src] (pipelined broadcast load); self scaled di.
// EPI: fused layer-1 epilogue out = dinv * relu(z + bias) (replaces gemm1's epilogue).
// 16B dwordx4 gathers, rotating 2-deep pipeline, weight-0 masked tail,
// cross-group shfl reduce, 16B stores by group 0.
template <int F, int SLICES, bool DSRC, bool EPI>
__global__ __launch_bounds__(256) void k_aggregate(const unsigned short* __restrict__ X,
                                                   const u64* __restrict__ deg_cnt,
                                                   const unsigned* __restrict__ edges,
                                                   const float* __restrict__ dinv,
                                                   unsigned short* __restrict__ Z,
                                                   const float* __restrict__ bias) {
    constexpr int FS = F / SLICES;     // features handled per block
    constexpr int LPR = FS / 8;        // lanes per source row-slice (16 or 32)
    constexpr int GRP = 64 / LPR;      // edges per step (4 or 2)
    constexpr int STEP = GRP * 2;      // edges per pair-iteration (8 or 4)
    const int bid = blockIdx.x;
    const int slice = (SLICES == 1) ? 0 : (bid & (SLICES - 1));
    const int chunk = (SLICES == 1) ? bid : (bid / SLICES);
    const int wave = threadIdx.x >> 6, lane = threadIdx.x & 63;
    const int node = chunk * 4 + wave;
    if (node >= NNODES) return;
    const int sub = lane & (LPR - 1);
    const int grp = lane / LPR;
    const int fo = slice * FS + sub * 8;
    const unsigned short* Xf = X + fo;
    const float di = dinv[node];
    const int cnt = (int)(deg_cnt[node] >> 32);
    const unsigned* erow = edges + ((unsigned)node << 6);

    // self row-slice: issue early, consumed in epilogue
    const uint4 selfv = *(const uint4*)(Xf + (size_t)node * F);

    float acc[8] = {};

    const int e0 = grp;
    const int nb = (cnt + STEP - 1) / STEP;   // pair-iterations (wave-uniform)

    unsigned pa0 = 0, pb0 = 0, pa1 = 0, pb1 = 0;
    uint4 va0 = {}, vb0 = {};
    float da0 = 1.f, db0 = 1.f;
    if (nb > 0) {
        int ea = e0, eb = e0 + GRP;
        pa0 = (ea < cnt) ? erow[ea] : 0u;
        pb0 = (eb < cnt) ? erow[eb] : 0u;
        va0 = *(const uint4*)(Xf + (size_t)(pa0 & 0xffffu) * F);
        vb0 = *(const uint4*)(Xf + (size_t)(pb0 & 0xffffu) * F);
        if constexpr (DSRC) { da0 = dinv[pa0 & 0xffffu]; db0 = dinv[pb0 & 0xffffu]; }
        if (nb > 1) {
            int ea1 = e0 + STEP, eb1 = ea1 + GRP;
            pa1 = (ea1 < cnt) ? erow[ea1] : 0u;
            pb1 = (eb1 < cnt) ? erow[eb1] : 0u;
        }
    }
    for (int p = 0; p < nb; ++p) {
        uint4 va1 = {}, vb1 = {};
        float da1 = 1.f, db1 = 1.f;
        unsigned pa2 = 0, pb2 = 0;
        if (p + 1 < nb) {
            va1 = *(const uint4*)(Xf + (size_t)(pa1 & 0xffffu) * F);
            vb1 = *(const uint4*)(Xf + (size_t)(pb1 & 0xffffu) * F);
            if constexpr (DSRC) { da1 = dinv[pa1 & 0xffffu]; db1 = dinv[pb1 & 0xffffu]; }
            if (p + 2 < nb) {
                int ea = e0 + (p + 2) * STEP, eb = ea + GRP;
                pa2 = (ea < cnt) ? erow[ea] : 0u;
                pb2 = (eb < cnt) ? erow[eb] : 0u;
            }
        }
        float ca = b2f((unsigned short)(pa0 >> 16));
        float cb = b2f((unsigned short)(pb0 >> 16));
        if constexpr (DSRC) { ca *= da0; cb *= db0; }
        accum8(acc, ca, va0);
        accum8(acc, cb, vb0);
        pa0 = pa1; pb0 = pb1; va0 = va1; vb0 = vb1;
        da0 = da1; db0 = db1;
        pa1 = pa2; pb1 = pb2;
    }

    // cross-group reduce
    #pragma unroll
    for (int j = 0; j < 8; ++j) {
        if constexpr (GRP == 4) acc[j] += __shfl_xor(acc[j], 16, 64);
        acc[j] += __shfl_xor(acc[j], 32, 64);
    }

    if (grp == 0) {
        float bv[8];
        if constexpr (EPI) {
            float4 q0 = *(const float4*)(bias + fo);
            float4 q1 = *(const float4*)(bias + fo + 4);
            bv[0] = q0.x; bv[1] = q0.y; bv[2] = q0.z; bv[3] = q0.w;
            bv[4] = q1.x; bv[5] = q1.y; bv[6] = q1.z; bv[7] = q1.w;
        }
        const float sc = DSRC ? di : 1.0f;   // self term scale (unscaled X path)
        unsigned w[4] = {selfv.x, selfv.y, selfv.z, selfv.w};
        unsigned o[4];
        #pragma unroll
        for (int i = 0; i < 4; ++i) {
            float s0 = __uint_as_float(w[i] << 16);
            float s1 = __uint_as_float(w[i] & 0xffff0000u);
            float z0 = di * (acc[2 * i] + sc * s0);
            float z1 = di * (acc[2 * i + 1] + sc * s1);
            if constexpr (EPI) {
                z0 = di * fmaxf(z0 + bv[2 * i], 0.f);
                z1 = di * fmaxf(z1 + bv[2 * i + 1], 0.f);
            }
            o[i] = (unsigned)f2b(z0) | ((unsigned)f2b(z1) << 16);
        }
        uint4 ov; ov.x = o[0]; ov.y = o[1]; ov.z = o[2]; ov.w = o[3];
        *(uint4*)(Z + (size_t)node * F + fo) = ov;
    }
}

// ---------- m97-structure GEMM, 2-phase double-buffered (T3-minimum) ----------
// 128x128 tile, 4 waves (2x2), each 64x64 = 4x4 16x16x32 fragments. BK=32.
// Double-buffered linear LDS [2][128][32]; next tile's global_load_lds issued BEFORE
// current tile's ds_read+MFMA; one vmcnt-drain barrier/tile. NPAD covers staging OOB
// (garbage rows only affect their own guarded outputs — MFMA rows are independent).
// Bijective XCD chunking (m204): each XCD owns a contiguous m-range for all n-blocks.
// CMODE 0: bf16 store + relu + optional rscale. 2: fused per-graph relu+max-pool.
template <int CMODE>
__global__ __launch_bounds__(256) void k_gemm128(const unsigned short* __restrict__ A,
                                                 const unsigned short* __restrict__ WT,
                                                 const float* __restrict__ bias,
                                                 unsigned short* __restrict__ C,
                                                 const int* __restrict__ batch,
                                                 int* __restrict__ gp,
                                                 const float* __restrict__ rscale,
                                                 int M, int N, int K) {
    __shared__ unsigned short As[2][128 * 32];
    __shared__ unsigned short Bs[2][128 * 32];
    const int tid = threadIdx.x;

    // bijective XCD remap of flat block id (xcd = f % 8 under round-robin dispatch)
    const int nwg = gridDim.x * gridDim.y;
    const int f = blockIdx.y * gridDim.x + blockIdx.x;
    const int q = nwg >> 3, r = nwg & 7;
    const int xcd = f & 7, idx = f >> 3;
    const int w = (xcd < r) ? xcd * (q + 1) + idx : r * (q + 1) + (xcd - r) * q + idx;
    const int m0 = (w / gridDim.x) * 128;
    const int n0 = (w % gridDim.x) * 128;

    const int wave = tid >> 6, lane = tid & 63;
    const int wm = (wave >> 1) * 64, wn = (wave & 1) * 64;
    const int quad = lane >> 4, mrow = lane & 15;

    const int sr = tid >> 2;              // staging row 0..63
    const int sc = (tid & 3) * 8;         // staging col (shorts)
    const unsigned short* Ag0 = A + (size_t)(m0 + sr) * K + sc;
    const unsigned short* Ag1 = A + (size_t)(m0 + 64 + sr) * K + sc;
    const unsigned short* Bg0 = WT + (size_t)(n0 + sr) * K + sc;
    const unsigned short* Bg1 = WT + (size_t)(n0 + 64 + sr) * K + sc;
    const int so0 = sr * 32 + sc, so1 = (64 + sr) * 32 + sc;

    f32x4 acc[4][4] = {};
    const int nsteps = K >> 5;

    // prologue: stage tile 0 into buffer 0
    GLOAD16(Ag0, &As[0][so0]);
    GLOAD16(Ag1, &As[0][so1]);
    GLOAD16(Bg0, &Bs[0][so0]);
    GLOAD16(Bg1, &Bs[0][so1]);
    __syncthreads();   // vmcnt(0) drain + barrier

    for (int step = 0; step < nsteps; ++step) {
        const int cur = step & 1;
        if (step + 1 < nsteps) {           // issue next tile while computing current
            const int k1 = (step + 1) << 5;
            GLOAD16(Ag0 + k1, &As[cur ^ 1][so0]);
            GLOAD16(Ag1 + k1, &As[cur ^ 1][so1]);
            GLOAD16(Bg0 + k1, &Bs[cur ^ 1][so0]);
            GLOAD16(Bg1 + k1, &Bs[cur ^ 1][so1]);
        }
        bf16x8 af[4], bf[4];
        #pragma unroll
        for (int mt = 0; mt < 4; ++mt)
            af[mt] = *(const bf16x8*)&As[cur][(wm + mt * 16 + mrow) * 32 + quad * 8];
        #pragma unroll
        for (int nt = 0; nt < 4; ++nt)
            bf[nt] = *(const bf16x8*)&Bs[cur][(wn + nt * 16 + mrow) * 32 + quad * 8];
        #pragma unroll
        for (int mt = 0; mt < 4; ++mt)
            #pragma unroll
            for (int nt = 0; nt < 4; ++nt)
                acc[mt][nt] = __builtin_amdgcn_mfma_f32_16x16x32_bf16(af[mt], bf[nt], acc[mt][nt], 0, 0, 0);
        __syncthreads();   // drains prefetch vmcnt + this tile's lgkm; gates buffer reuse
    }

    float bn[4];
    #pragma unroll
    for (int nt = 0; nt < 4; ++nt) bn[nt] = bias[n0 + wn + nt * 16 + mrow];

    if constexpr (CMODE == 0) {
        #pragma unroll
        for (int mt = 0; mt < 4; ++mt) {
            #pragma unroll
            for (int r4 = 0; r4 < 4; ++r4) {
                int row = m0 + wm + mt * 16 + quad * 4 + r4;
                if (row < M) {
                    float rs = rscale ? rscale[row] : 1.0f;
                    #pragma unroll
                    for (int nt = 0; nt < 4; ++nt) {
                        float v = fmaxf(acc[mt][nt][r4] + bn[nt], 0.f) * rs;
                        C[(size_t)row * N + n0 + wn + nt * 16 + mrow] = f2b(v);
                    }
                }
            }
        }
    } else {
        // per-wave pool: wave covers 64 rows -> spans <=2 graphs (min graph size 97)
        const int wr0 = m0 + wm;
        int g0i = wr0 < M ? wr0 : M - 1;
        const int g0 = batch[g0i];
        int lastr = wr0 + 63; if (lastr >= M) lastr = M - 1;
        const int gl = batch[lastr];
        bool rok[16]; int gid[16];
        #pragma unroll
        for (int mt = 0; mt < 4; ++mt)
            #pragma unroll
            for (int r4 = 0; r4 < 4; ++r4) {
                int row = wr0 + mt * 16 + quad * 4 + r4;
                rok[mt * 4 + r4] = row < M;
                gid[mt * 4 + r4] = (row < M) ? batch[row] : -1;
            }
        #pragma unroll
        for (int nt = 0; nt < 4; ++nt) {
            float v0 = 0.f, v1 = 0.f;
            #pragma unroll
            for (int mt = 0; mt < 4; ++mt)
                #pragma unroll
                for (int r4 = 0; r4 < 4; ++r4)
                    if (rok[mt * 4 + r4]) {
                        float v = fmaxf(acc[mt][nt][r4] + bn[nt], 0.f);
                        if (gid[mt * 4 + r4] == g0) v0 = fmaxf(v0, v);
                        else v1 = fmaxf(v1, v);
                    }
            v0 = fmaxf(v0, __shfl_xor(v0, 16, 64));
            v0 = fmaxf(v0, __shfl_xor(v0, 32, 64));
            v1 = fmaxf(v1, __shfl_xor(v1, 16, 64));
            v1 = fmaxf(v1, __shfl_xor(v1, 32, 64));
            if (quad == 0) {
                int c = n0 + wn + nt * 16 + mrow;
                atomicMax(&gp[(size_t)g0 * N + c], __float_as_int(v0));
                if (gl != g0) atomicMax(&gp[(size_t)gl * N + c], __float_as_int(v1));
            }
        }
    }
}

// ---------- legacy GEMM for the small MLP head (M=512) ----------
// block 64(M) x 128(N), 4 waves (2x2 of 32x64), BK=32, 16x16x32 MFMA.
// CMODE 0: bf16 store + relu. 1: fp32 store, no relu. AFP: A is fp32.
template <int CMODE, int AFP>
__global__ __launch_bounds__(256) void k_gemm_mfma(const void* __restrict__ Av,
                                                   const unsigned short* __restrict__ WT,
                                                   const float* __restrict__ bias,
                                                   void* __restrict__ Cv,
                                                   int M, int N, int K) {
    constexpr int LDK = 40;
    __shared__ unsigned short As[64 * LDK];
    __shared__ unsigned short Bs[128 * LDK];
    const int tid = threadIdx.x;
    const int m0 = blockIdx.y * 64, n0 = blockIdx.x * 128;
    const int wave = tid >> 6, lane = tid & 63;
    const int wm = (wave >> 1) * 32;
    const int wn = (wave & 1) * 64;
    const int quad = lane >> 4, mrow = lane & 15;

    const int ar = tid >> 2;
    const int ak = (tid & 3) * 8;
    const bool arow_ok = (m0 + ar) < M;
    const size_t aoff = (size_t)(m0 + ar) * K + ak;
    const unsigned short* Bg0 = WT + (size_t)(n0 + ar) * K + ak;
    const unsigned short* Bg1 = WT + (size_t)(n0 + ar + 64) * K + ak;

    f32x4 acc[2][4] = {};

    for (int k0 = 0; k0 < K; k0 += 32) {
        u16x8 av = {};
        if (arow_ok) {
            if constexpr (AFP) {
                const float* Af = (const float*)Av + aoff + k0;
                float4 f0 = *(const float4*)Af;
                float4 f1 = *(const float4*)(Af + 4);
                av[0] = (short)f2b(f0.x); av[1] = (short)f2b(f0.y);
                av[2] = (short)f2b(f0.z); av[3] = (short)f2b(f0.w);
                av[4] = (short)f2b(f1.x); av[5] = (short)f2b(f1.y);
                av[6] = (short)f2b(f1.z); av[7] = (short)f2b(f1.w);
            } else {
                av = *(const u16x8*)((const unsigned short*)Av + aoff + k0);
            }
        }
        u16x8 bv0 = *(const u16x8*)(Bg0 + k0);
        u16x8 bv1 = *(const u16x8*)(Bg1 + k0);
        *(u16x8*)&As[ar * LDK + ak] = av;
        *(u16x8*)&Bs[ar * LDK + ak] = bv0;
        *(u16x8*)&Bs[(ar + 64) * LDK + ak] = bv1;
        __syncthreads();
        bf16x8 af[2], bf[4];
        #pragma unroll
        for (int mt = 0; mt < 2; ++mt)
            af[mt] = *(const bf16x8*)&As[(wm + mt * 16 + mrow) * LDK + quad * 8];
        #pragma unroll
        for (int nt = 0; nt < 4; ++nt)
            bf[nt] = *(const bf16x8*)&Bs[(wn + nt * 16 + mrow) * LDK + quad * 8];
        #pragma unroll
        for (int mt = 0; mt < 2; ++mt)
            #pragma unroll
            for (int nt = 0; nt < 4; ++nt)
                acc[mt][nt] = __builtin_amdgcn_mfma_f32_16x16x32_bf16(af[mt], bf[nt], acc[mt][nt], 0, 0, 0);
        __syncthreads();
    }

    float bn[4];
    #pragma unroll
    for (int nt = 0; nt < 4; ++nt) bn[nt] = bias[n0 + wn + nt * 16 + mrow];

    if constexpr (CMODE == 0) {
        unsigned short* C = (unsigned short*)Cv;
        #pragma unroll
        for (int mt = 0; mt < 2; ++mt) {
            #pragma unroll
            for (int r = 0; r < 4; ++r) {
                int row = m0 + wm + mt * 16 + quad * 4 + r;
                if (row < M) {
                    #pragma unroll
                    for (int nt = 0; nt < 4; ++nt) {
                        float v = fmaxf(acc[mt][nt][r] + bn[nt], 0.f);
                        C[(size_t)row * N + n0 + wn + nt * 16 + mrow] = f2b(v);
                    }
                }
            }
        }
    } else {
        float* C = (float*)Cv;
        #pragma unroll
        for (int mt = 0; mt < 2; ++mt) {
            #pragma unroll
            for (int r = 0; r < 4; ++r) {
                int row = m0 + wm + mt * 16 + quad * 4 + r;
                if (row < M) {
                    #pragma unroll
                    for (int nt = 0; nt < 4; ++nt)
                        C[(size_t)row * N + n0 + wn + nt * 16 + mrow] = acc[mt][nt][r] + bn[nt];
                }
            }
        }
    }
}

extern "C" void kernel_launch(void* const* d_in, const int* in_sizes, int n_in,
                              void* d_out, int out_size, void* d_ws, size_t ws_size,
                              hipStream_t stream) {
    const float* x   = (const float*)d_in[0];
    const float* ew  = (const float*)d_in[1];
    const float* W1  = (const float*)d_in[2];
    const float* b1  = (const float*)d_in[3];
    const float* W2  = (const float*)d_in[4];
    const float* b2  = (const float*)d_in[5];
    const float* W3  = (const float*)d_in[6];
    const float* b3  = (const float*)d_in[7];
    const float* Wf1 = (const float*)d_in[8];
    const float* bf1 = (const float*)d_in[9];
    const float* Wf2 = (const float*)d_in[10];
    const float* bf2 = (const float*)d_in[11];
    const int* ei    = (const int*)d_in[12];
    const int* batch = (const int*)d_in[13];
    float* out = (float*)d_out;
    (void)in_sizes; (void)n_in; (void)out_size; (void)ws_size;

    char* p = (char*)d_ws;
    auto alloc = [&](size_t bytes) -> char* {
        char* r = p;
        p += (bytes + 255) & ~(size_t)255;
        return r;
    };
    u64*   deg_cnt = (u64*)alloc((size_t)NNODES * 8);
    float* dinv   = (float*)alloc((size_t)NNODES * 4);
    unsigned* edges = (unsigned*)alloc((size_t)NNODES * DCAP * 4);  // padded CSR, 12.8 MB
    int*   gp     = (int*)  alloc((size_t)NGRAPH * 512 * 4);
    unsigned short* f1   = (unsigned short*)alloc((size_t)NGRAPH * 1024 * 2);
    unsigned short* wt2  = (unsigned short*)alloc((size_t)256 * 128 * 2);
    unsigned short* wt3  = (unsigned short*)alloc((size_t)512 * 256 * 2);
    unsigned short* wtf1 = (unsigned short*)alloc((size_t)1024 * 512 * 2);
    unsigned short* wtf2 = (unsigned short*)alloc((size_t)128 * 1024 * 2);
    unsigned short* bufA = (unsigned short*)alloc((size_t)NPAD * 256 * 2);
    unsigned short* bufB = (unsigned short*)alloc((size_t)NPAD * 256 * 2);
    unsigned short* P1   = bufB;   // layer-1 pre-GEMM result (consumed by agg1)
    // total ~68 MB

    const int MB128 = (NNODES + 127) / 128; // 391
    const int AGG = (NNODES + 3) / 4;       // 12500

    // preprocessing: memset + fused k_pre (edges + P1 GEMM + transposes) + k_prep
    hipMemsetAsync(deg_cnt, 0, (size_t)NNODES * 8, stream);
    k_pre<<<EBLK + GBLK + TBLK, 256, 0, stream>>>(W1, W2, W3, Wf1, Wf2,
                                                  wt2, wt3, wtf1, wtf2,
                                                  (const int4*)ei, (const int4*)(ei + NEDGES),
                                                  (const float4*)ew, deg_cnt, edges, x, P1);
    k_prep<<<1024, 256, 0, stream>>>(deg_cnt, dinv, gp);

    // layer 1: H1' = dinv * relu( A_hat @ P1 + b1 )  — gemm1 eliminated (P1 under the wall)
    k_aggregate<128, 1, true, true><<<AGG, 256, 0, stream>>>(P1, deg_cnt, edges, dinv, bufA, b1);
    // layer 2
    k_aggregate<128, 1, false, false><<<AGG, 256, 0, stream>>>(bufA, deg_cnt, edges, dinv, bufB, nullptr);
    k_gemm128<0><<<dim3(2, MB128), 256, 0, stream>>>(bufB, wt2, b2, bufA, nullptr, nullptr, dinv, NNODES, 256, 128);
    // layer 3 + fused pool (unscaled relu feeds the pool); feature-sliced aggregate (S=2)
    k_aggregate<256, 2, false, false><<<AGG * 2, 256, 0, stream>>>(bufA, deg_cnt, edges, dinv, bufB, nullptr);
    k_gemm128<2><<<dim3(4, MB128), 256, 0, stream>>>(bufB, wt3, b3, nullptr, batch, gp, nullptr, NNODES, 512, 256);

    // MLP head (legacy kernel, M=512)
    k_gemm_mfma<0, 1><<<dim3(8, NGRAPH / 64), 256, 0, stream>>>(gp, wtf1, bf1, f1, NGRAPH, 1024, 512);
    k_gemm_mfma<1, 0><<<dim3(1, NGRAPH / 64), 256, 0, stream>>>(f1, wtf2, bf2, out, NGRAPH, 128, 1024);
}

// Round 13
// 352.070 us; speedup vs baseline: 1.0707x; 1.0138x over previous
//
#include <hip/hip_runtime.h>

#define NNODES 50000
#define NPAD   50048   // 391 * 128; padded row count so 128-tile GEMM staging never faults
#define NEDGES 800000
#define NGRAPH 512
#define DCAP 64   // padded edge slots per node; Poisson(16) max ~37, P(>=64) ~ 1e-23

typedef short bf16x8 __attribute__((ext_vector_type(8)));
typedef unsigned short u16x8 __attribute__((ext_vector_type(8)));
typedef float f32x4 __attribute__((ext_vector_type(4)));
typedef unsigned long long u64;

// async global->LDS, 16B per lane (dest = wave-uniform base + lane*16, linear layout)
#define GLOAD16(g, l)                                                                 \
    __builtin_amdgcn_global_load_lds((const __attribute__((address_space(1))) unsigned*)(g), \
                                     (__attribute__((address_space(3))) unsigned*)(l), 16, 0, 0)

// ---------- bf16 <-> fp32 helpers ----------
static __device__ __forceinline__ float b2f(unsigned short u) {
    return __uint_as_float(((unsigned)u) << 16);
}
static __device__ __forceinline__ unsigned short f2b(float f) {
    unsigned u = __float_as_uint(f);
    unsigned r = (u + 0x7fffu + ((u >> 16) & 1u)) >> 16;  // round-nearest-even
    return (unsigned short)r;
}

// accumulate 8 bf16 (packed in uint4) * c into acc[8]
static __device__ __forceinline__ void accum8(float (&acc)[8], float c, uint4 v) {
    unsigned w[4] = {v.x, v.y, v.z, v.w};
    #pragma unroll
    for (int i = 0; i < 4; ++i) {
        acc[2 * i]     += c * __uint_as_float(w[i] << 16);
        acc[2 * i + 1] += c * __uint_as_float(w[i] & 0xffff0000u);
    }
}

// ---------- fused preprocessing under the atomic wall (r10-proven form) ----------
// Edge placement is memory-side atomic/scatter-store-bound (~57us, all pipes idle).
// Light streaming work rides under it for free (r10: transposes+cvt added 0us).
// r11/r12 lesson: HEAVY work does NOT ride free — the P1-GEMM branch raised the
// kernel-wide VGPR to 64 (halving the wall's resident waves) and swept W1 through
// L1/L2 782x, stretching the wall 57->72us. P1-GEMM is now a separate dispatch.
#define EBLK 782   // ceil(200000/256) edge blocks (4 edges/thread)
#define TBLK 204   // transpose tiles: W1 4, W2 8, W3 32, Wf1 128, Wf2 32
__global__ __launch_bounds__(256) void k_pre(const float* __restrict__ W1, const float* __restrict__ W2,
                                             const float* __restrict__ W3, const float* __restrict__ Wf1,
                                             const float* __restrict__ Wf2,
                                             unsigned short* __restrict__ T1, unsigned short* __restrict__ T2,
                                             unsigned short* __restrict__ T3, unsigned short* __restrict__ Tf1,
                                             unsigned short* __restrict__ Tf2,
                                             const int4* __restrict__ ei_s, const int4* __restrict__ ei_d,
                                             const float4* __restrict__ ew4,
                                             u64* deg_cnt, unsigned* __restrict__ edges) {
    __shared__ float sm[64][65];   // transpose branch only (16.6KB)
    const int b = blockIdx.x;
    const int tid = threadIdx.x;
    if (b < EBLK) {
        // edge placement: u64 atomic returns old count = this edge's slot; 4 chains/thread
        int t = b * 256 + tid;
        if (t >= NEDGES / 4) return;
        int4 ss = ei_s[t];
        int4 dd = ei_d[t];
        float4 ww = ew4[t];
        int s[4] = {ss.x, ss.y, ss.z, ss.w};
        int d[4] = {dd.x, dd.y, dd.z, dd.w};
        float w[4] = {ww.x, ww.y, ww.z, ww.w};
        int slot[4];
        #pragma unroll
        for (int u = 0; u < 4; ++u) {
            unsigned fixed = __float2uint_rn(w[u] * 16777216.0f);  // 8.24 fixed; ew in [0,1)
            u64 old = atomicAdd(&deg_cnt[d[u]], ((u64)1 << 32) | fixed);
            slot[u] = (int)(old >> 32);
            if (slot[u] > DCAP - 1) slot[u] = DCAP - 1;  // never fires (safety)
        }
        #pragma unroll
        for (int u = 0; u < 4; ++u)
            edges[((unsigned)d[u] << 6) | slot[u]] = ((unsigned)f2b(w[u]) << 16) | (unsigned)s[u];
        return;
    }
    // ---- W[K][N] fp32 -> WT[N][K] bf16, 64x64 LDS tile, both sides coalesced ----
    const int bb = b - EBLK;
    if (bb >= TBLK) return;
    const float* W; unsigned short* T; int K, N, t0;
    if (bb < 4)        { W = W1;  T = T1;  K = 128;  N = 128;  t0 = 0;   }
    else if (bb < 12)  { W = W2;  T = T2;  K = 128;  N = 256;  t0 = 4;   }
    else if (bb < 44)  { W = W3;  T = T3;  K = 256;  N = 512;  t0 = 12;  }
    else if (bb < 172) { W = Wf1; T = Tf1; K = 512;  N = 1024; t0 = 44;  }
    else               { W = Wf2; T = Tf2; K = 1024; N = 128;  t0 = 172; }
    const int tile = bb - t0;
    const int ntn = N >> 6;
    const int k0 = (tile / ntn) * 64, n0 = (tile % ntn) * 64;
    const int rr = tid >> 6, cc = tid & 63;
    #pragma unroll
    for (int r = 0; r < 16; ++r) {
        int kl = r * 4 + rr;
        sm[kl][cc] = W[(size_t)(k0 + kl) * N + n0 + cc];
    }
    __syncthreads();
    #pragma unroll
    for (int r = 0; r < 16; ++r) {
        int nl = r * 4 + rr;
        T[(size_t)(n0 + nl) * K + k0 + cc] = f2b(sm[cc][nl]);
    }
}

// dinv from packed degree (+1.0 self-loop folded in) + gp zero
__global__ void k_prep(const u64* __restrict__ deg_cnt, float* __restrict__ dinv, int* __restrict__ gp) {
    int i = blockIdx.x * 256 + threadIdx.x;
    if (i < NNODES)
        dinv[i] = rsqrtf((float)(unsigned)(deg_cnt[i] & 0xffffffffull) * 5.9604645e-8f + 1.0f);
    if (i < NGRAPH * 512) gp[i] = 0;   // +0.0f bits; relu pool >= 0
}

// ---------- aggregation: Z[d,:] = epi( dinv[d] * (self + sum_e c_e * X[src_e,:]) ) ----------
// wave-per-(node, feature-slice). SLICES=2 (F=256): slice parity == XCD parity under
// round-robin dispatch -> 12.8MB half-table per XCD L2 (r8: FETCH 187->162MB).
// DSRC: X unscaled -> c_e = w_e * dinv[src] (pipelined broadcast load); self scaled di.
// EPI: fused layer-1 epilogue out = dinv * relu(z + bias) (replaces gemm1's epilogue).
// 16B dwordx4 gathers, rotating 2-deep pipeline, weight-0 masked tail,
// cross-group shfl reduce, 16B stores by group 0.
template <int F, int SLICES, bool DSRC, bool EPI>
__global__ __launch_bounds__(256) void k_aggregate(const unsigned short* __restrict__ X,
                                                   const u64* __restrict__ deg_cnt,
                                                   const unsigned* __restrict__ edges,
                                                   const float* __restrict__ dinv,
                                                   unsigned short* __restrict__ Z,
                                                   const float* __restrict__ bias) {
    constexpr int FS = F / SLICES;     // features handled per block
    constexpr int LPR = FS / 8;        // lanes per source row-slice (16 or 32)
    constexpr int GRP = 64 / LPR;      // edges per step (4 or 2)
    constexpr int STEP = GRP * 2;      // edges per pair-iteration (8 or 4)
    const int bid = blockIdx.x;
    const int slice = (SLICES == 1) ? 0 : (bid & (SLICES - 1));
    const int chunk = (SLICES == 1) ? bid : (bid / SLICES);
    const int wave = threadIdx.x >> 6, lane = threadIdx.x & 63;
    const int node = chunk * 4 + wave;
    if (node >= NNODES) return;
    const int sub = lane & (LPR - 1);
    const int grp = lane / LPR;
    const int fo = slice * FS + sub * 8;
    const unsigned short* Xf = X + fo;
    const float di = dinv[node];
    const int cnt = (int)(deg_cnt[node] >> 32);
    const unsigned* erow = edges + ((unsigned)node << 6);

    // self row-slice: issue early, consumed in epilogue
    const uint4 selfv = *(const uint4*)(Xf + (size_t)node * F);

    float acc[8] = {};

    const int e0 = grp;
    const int nb = (cnt + STEP - 1) / STEP;   // pair-iterations (wave-uniform)

    unsigned pa0 = 0, pb0 = 0, pa1 = 0, pb1 = 0;
    uint4 va0 = {}, vb0 = {};
    float da0 = 1.f, db0 = 1.f;
    if (nb > 0) {
        int ea = e0, eb = e0 + GRP;
        pa0 = (ea < cnt) ? erow[ea] : 0u;
        pb0 = (eb < cnt) ? erow[eb] : 0u;
        va0 = *(const uint4*)(Xf + (size_t)(pa0 & 0xffffu) * F);
        vb0 = *(const uint4*)(Xf + (size_t)(pb0 & 0xffffu) * F);
        if constexpr (DSRC) { da0 = dinv[pa0 & 0xffffu]; db0 = dinv[pb0 & 0xffffu]; }
        if (nb > 1) {
            int ea1 = e0 + STEP, eb1 = ea1 + GRP;
            pa1 = (ea1 < cnt) ? erow[ea1] : 0u;
            pb1 = (eb1 < cnt) ? erow[eb1] : 0u;
        }
    }
    for (int p = 0; p < nb; ++p) {
        uint4 va1 = {}, vb1 = {};
        float da1 = 1.f, db1 = 1.f;
        unsigned pa2 = 0, pb2 = 0;
        if (p + 1 < nb) {
            va1 = *(const uint4*)(Xf + (size_t)(pa1 & 0xffffu) * F);
            vb1 = *(const uint4*)(Xf + (size_t)(pb1 & 0xffffu) * F);
            if constexpr (DSRC) { da1 = dinv[pa1 & 0xffffu]; db1 = dinv[pb1 & 0xffffu]; }
            if (p + 2 < nb) {
                int ea = e0 + (p + 2) * STEP, eb = ea + GRP;
                pa2 = (ea < cnt) ? erow[ea] : 0u;
                pb2 = (eb < cnt) ? erow[eb] : 0u;
            }
        }
        float ca = b2f((unsigned short)(pa0 >> 16));
        float cb = b2f((unsigned short)(pb0 >> 16));
        if constexpr (DSRC) { ca *= da0; cb *= db0; }
        accum8(acc, ca, va0);
        accum8(acc, cb, vb0);
        pa0 = pa1; pb0 = pb1; va0 = va1; vb0 = vb1;
        da0 = da1; db0 = db1;
        pa1 = pa2; pb1 = pb2;
    }

    // cross-group reduce
    #pragma unroll
    for (int j = 0; j < 8; ++j) {
        if constexpr (GRP == 4) acc[j] += __shfl_xor(acc[j], 16, 64);
        acc[j] += __shfl_xor(acc[j], 32, 64);
    }

    if (grp == 0) {
        float bv[8];
        if constexpr (EPI) {
            float4 q0 = *(const float4*)(bias + fo);
            float4 q1 = *(const float4*)(bias + fo + 4);
            bv[0] = q0.x; bv[1] = q0.y; bv[2] = q0.z; bv[3] = q0.w;
            bv[4] = q1.x; bv[5] = q1.y; bv[6] = q1.z; bv[7] = q1.w;
        }
        const float sc = DSRC ? di : 1.0f;   // self term scale (unscaled X path)
        unsigned w[4] = {selfv.x, selfv.y, selfv.z, selfv.w};
        unsigned o[4];
        #pragma unroll
        for (int i = 0; i < 4; ++i) {
            float s0 = __uint_as_float(w[i] << 16);
            float s1 = __uint_as_float(w[i] & 0xffff0000u);
            float z0 = di * (acc[2 * i] + sc * s0);
            float z1 = di * (acc[2 * i + 1] + sc * s1);
            if constexpr (EPI) {
                z0 = di * fmaxf(z0 + bv[2 * i], 0.f);
                z1 = di * fmaxf(z1 + bv[2 * i + 1], 0.f);
            }
            o[i] = (unsigned)f2b(z0) | ((unsigned)f2b(z1) << 16);
        }
        uint4 ov; ov.x = o[0]; ov.y = o[1]; ov.z = o[2]; ov.w = o[3];
        *(uint4*)(Z + (size_t)node * F + fo) = ov;
    }
}

// ---------- m97-structure GEMM, 2-phase double-buffered (T3-minimum) ----------
// 128x128 tile, 4 waves (2x2), each 64x64 = 4x4 16x16x32 fragments. BK=32.
// Double-buffered linear LDS [2][128][32]; next tile's global_load_lds issued BEFORE
// current tile's ds_read+MFMA; one vmcnt-drain barrier/tile. NPAD covers staging OOB
// (garbage rows only affect their own guarded outputs — MFMA rows are independent).
// Bijective XCD chunking (m204): each XCD owns a contiguous m-range for all n-blocks.
// CMODE 0: bf16 store + relu + optional rscale. 2: fused per-graph relu+max-pool.
template <int CMODE>
__global__ __launch_bounds__(256) void k_gemm128(const unsigned short* __restrict__ A,
                                                 const unsigned short* __restrict__ WT,
                                                 const float* __restrict__ bias,
                                                 unsigned short* __restrict__ C,
                                                 const int* __restrict__ batch,
                                                 int* __restrict__ gp,
                                                 const float* __restrict__ rscale,
                                                 int M, int N, int K) {
    __shared__ unsigned short As[2][128 * 32];
    __shared__ unsigned short Bs[2][128 * 32];
    const int tid = threadIdx.x;

    // bijective XCD remap of flat block id (xcd = f % 8 under round-robin dispatch)
    const int nwg = gridDim.x * gridDim.y;
    const int f = blockIdx.y * gridDim.x + blockIdx.x;
    const int q = nwg >> 3, r = nwg & 7;
    const int xcd = f & 7, idx = f >> 3;
    const int w = (xcd < r) ? xcd * (q + 1) + idx : r * (q + 1) + (xcd - r) * q + idx;
    const int m0 = (w / gridDim.x) * 128;
    const int n0 = (w % gridDim.x) * 128;

    const int wave = tid >> 6, lane = tid & 63;
    const int wm = (wave >> 1) * 64, wn = (wave & 1) * 64;
    const int quad = lane >> 4, mrow = lane & 15;

    const int sr = tid >> 2;              // staging row 0..63
    const int sc = (tid & 3) * 8;         // staging col (shorts)
    const unsigned short* Ag0 = A + (size_t)(m0 + sr) * K + sc;
    const unsigned short* Ag1 = A + (size_t)(m0 + 64 + sr) * K + sc;
    const unsigned short* Bg0 = WT + (size_t)(n0 + sr) * K + sc;
    const unsigned short* Bg1 = WT + (size_t)(n0 + 64 + sr) * K + sc;
    const int so0 = sr * 32 + sc, so1 = (64 + sr) * 32 + sc;

    f32x4 acc[4][4] = {};
    const int nsteps = K >> 5;

    // prologue: stage tile 0 into buffer 0
    GLOAD16(Ag0, &As[0][so0]);
    GLOAD16(Ag1, &As[0][so1]);
    GLOAD16(Bg0, &Bs[0][so0]);
    GLOAD16(Bg1, &Bs[0][so1]);
    __syncthreads();   // vmcnt(0) drain + barrier

    for (int step = 0; step < nsteps; ++step) {
        const int cur = step & 1;
        if (step + 1 < nsteps) {           // issue next tile while computing current
            const int k1 = (step + 1) << 5;
            GLOAD16(Ag0 + k1, &As[cur ^ 1][so0]);
            GLOAD16(Ag1 + k1, &As[cur ^ 1][so1]);
            GLOAD16(Bg0 + k1, &Bs[cur ^ 1][so0]);
            GLOAD16(Bg1 + k1, &Bs[cur ^ 1][so1]);
        }
        bf16x8 af[4], bf[4];
        #pragma unroll
        for (int mt = 0; mt < 4; ++mt)
            af[mt] = *(const bf16x8*)&As[cur][(wm + mt * 16 + mrow) * 32 + quad * 8];
        #pragma unroll
        for (int nt = 0; nt < 4; ++nt)
            bf[nt] = *(const bf16x8*)&Bs[cur][(wn + nt * 16 + mrow) * 32 + quad * 8];
        #pragma unroll
        for (int mt = 0; mt < 4; ++mt)
            #pragma unroll
            for (int nt = 0; nt < 4; ++nt)
                acc[mt][nt] = __builtin_amdgcn_mfma_f32_16x16x32_bf16(af[mt], bf[nt], acc[mt][nt], 0, 0, 0);
        __syncthreads();   // drains prefetch vmcnt + this tile's lgkm; gates buffer reuse
    }

    float bn[4];
    #pragma unroll
    for (int nt = 0; nt < 4; ++nt) bn[nt] = bias[n0 + wn + nt * 16 + mrow];

    if constexpr (CMODE == 0) {
        #pragma unroll
        for (int mt = 0; mt < 4; ++mt) {
            #pragma unroll
            for (int r4 = 0; r4 < 4; ++r4) {
                int row = m0 + wm + mt * 16 + quad * 4 + r4;
                if (row < M) {
                    float rs = rscale ? rscale[row] : 1.0f;
                    #pragma unroll
                    for (int nt = 0; nt < 4; ++nt) {
                        float v = fmaxf(acc[mt][nt][r4] + bn[nt], 0.f) * rs;
                        C[(size_t)row * N + n0 + wn + nt * 16 + mrow] = f2b(v);
                    }
                }
            }
        }
    } else {
        // per-wave pool: wave covers 64 rows -> spans <=2 graphs (min graph size 97)
        const int wr0 = m0 + wm;
        int g0i = wr0 < M ? wr0 : M - 1;
        const int g0 = batch[g0i];
        int lastr = wr0 + 63; if (lastr >= M) lastr = M - 1;
        const int gl = batch[lastr];
        bool rok[16]; int gid[16];
        #pragma unroll
        for (int mt = 0; mt < 4; ++mt)
            #pragma unroll
            for (int r4 = 0; r4 < 4; ++r4) {
                int row = wr0 + mt * 16 + quad * 4 + r4;
                rok[mt * 4 + r4] = row < M;
                gid[mt * 4 + r4] = (row < M) ? batch[row] : -1;
            }
        #pragma unroll
        for (int nt = 0; nt < 4; ++nt) {
            float v0 = 0.f, v1 = 0.f;
            #pragma unroll
            for (int mt = 0; mt < 4; ++mt)
                #pragma unroll
                for (int r4 = 0; r4 < 4; ++r4)
                    if (rok[mt * 4 + r4]) {
                        float v = fmaxf(acc[mt][nt][r4] + bn[nt], 0.f);
                        if (gid[mt * 4 + r4] == g0) v0 = fmaxf(v0, v);
                        else v1 = fmaxf(v1, v);
                    }
            v0 = fmaxf(v0, __shfl_xor(v0, 16, 64));
            v0 = fmaxf(v0, __shfl_xor(v0, 32, 64));
            v1 = fmaxf(v1, __shfl_xor(v1, 16, 64));
            v1 = fmaxf(v1, __shfl_xor(v1, 32, 64));
            if (quad == 0) {
                int c = n0 + wn + nt * 16 + mrow;
                atomicMax(&gp[(size_t)g0 * N + c], __float_as_int(v0));
                if (gl != g0) atomicMax(&gp[(size_t)gl * N + c], __float_as_int(v1));
            }
        }
    }
}

// ---------- legacy GEMM: MLP head (M=512) and P1 = X@W1 pre-GEMM ----------
// block 64(M) x 128(N), 4 waves (2x2 of 32x64), BK=32, 16x16x32 MFMA.
// CMODE 0: bf16 store + relu. 1: fp32 store, no relu. 3: bf16 store, NO relu, NO bias
// (raw X@W1; bias+relu applied in agg1's EPI). AFP: A is fp32.
template <int CMODE, int AFP>
__global__ __launch_bounds__(256) void k_gemm_mfma(const void* __restrict__ Av,
                                                   const unsigned short* __restrict__ WT,
                                                   const float* __restrict__ bias,
                                                   void* __restrict__ Cv,
                                                   int M, int N, int K) {
    constexpr int LDK = 40;
    __shared__ unsigned short As[64 * LDK];
    __shared__ unsigned short Bs[128 * LDK];
    const int tid = threadIdx.x;
    const int m0 = blockIdx.y * 64, n0 = blockIdx.x * 128;
    const int wave = tid >> 6, lane = tid & 63;
    const int wm = (wave >> 1) * 32;
    const int wn = (wave & 1) * 64;
    const int quad = lane >> 4, mrow = lane & 15;

    const int ar = tid >> 2;
    const int ak = (tid & 3) * 8;
    const bool arow_ok = (m0 + ar) < M;
    const size_t aoff = (size_t)(m0 + ar) * K + ak;
    const unsigned short* Bg0 = WT + (size_t)(n0 + ar) * K + ak;
    const unsigned short* Bg1 = WT + (size_t)(n0 + ar + 64) * K + ak;

    f32x4 acc[2][4] = {};

    for (int k0 = 0; k0 < K; k0 += 32) {
        u16x8 av = {};
        if (arow_ok) {
            if constexpr (AFP) {
                const float* Af = (const float*)Av + aoff + k0;
                float4 f0 = *(const float4*)Af;
                float4 f1 = *(const float4*)(Af + 4);
                av[0] = (short)f2b(f0.x); av[1] = (short)f2b(f0.y);
                av[2] = (short)f2b(f0.z); av[3] = (short)f2b(f0.w);
                av[4] = (short)f2b(f1.x); av[5] = (short)f2b(f1.y);
                av[6] = (short)f2b(f1.z); av[7] = (short)f2b(f1.w);
            } else {
                av = *(const u16x8*)((const unsigned short*)Av + aoff + k0);
            }
        }
        u16x8 bv0 = *(const u16x8*)(Bg0 + k0);
        u16x8 bv1 = *(const u16x8*)(Bg1 + k0);
        *(u16x8*)&As[ar * LDK + ak] = av;
        *(u16x8*)&Bs[ar * LDK + ak] = bv0;
        *(u16x8*)&Bs[(ar + 64) * LDK + ak] = bv1;
        __syncthreads();
        bf16x8 af[2], bf[4];
        #pragma unroll
        for (int mt = 0; mt < 2; ++mt)
            af[mt] = *(const bf16x8*)&As[(wm + mt * 16 + mrow) * LDK + quad * 8];
        #pragma unroll
        for (int nt = 0; nt < 4; ++nt)
            bf[nt] = *(const bf16x8*)&Bs[(wn + nt * 16 + mrow) * LDK + quad * 8];
        #pragma unroll
        for (int mt = 0; mt < 2; ++mt)
            #pragma unroll
            for (int nt = 0; nt < 4; ++nt)
                acc[mt][nt] = __builtin_amdgcn_mfma_f32_16x16x32_bf16(af[mt], bf[nt], acc[mt][nt], 0, 0, 0);
        __syncthreads();
    }

    float bn[4] = {0.f, 0.f, 0.f, 0.f};
    if constexpr (CMODE != 3) {
        #pragma unroll
        for (int nt = 0; nt < 4; ++nt) bn[nt] = bias[n0 + wn + nt * 16 + mrow];
    }

    if constexpr (CMODE == 0) {
        unsigned short* C = (unsigned short*)Cv;
        #pragma unroll
        for (int mt = 0; mt < 2; ++mt) {
            #pragma unroll
            for (int r = 0; r < 4; ++r) {
                int row = m0 + wm + mt * 16 + quad * 4 + r;
                if (row < M) {
                    #pragma unroll
                    for (int nt = 0; nt < 4; ++nt) {
                        float v = fmaxf(acc[mt][nt][r] + bn[nt], 0.f);
                        C[(size_t)row * N + n0 + wn + nt * 16 + mrow] = f2b(v);
                    }
                }
            }
        }
    } else if constexpr (CMODE == 1) {
        float* C = (float*)Cv;
        #pragma unroll
        for (int mt = 0; mt < 2; ++mt) {
            #pragma unroll
            for (int r = 0; r < 4; ++r) {
                int row = m0 + wm + mt * 16 + quad * 4 + r;
                if (row < M) {
                    #pragma unroll
                    for (int nt = 0; nt < 4; ++nt)
                        C[(size_t)row * N + n0 + wn + nt * 16 + mrow] = acc[mt][nt][r] + bn[nt];
                }
            }
        }
    } else {
        unsigned short* C = (unsigned short*)Cv;
        #pragma unroll
        for (int mt = 0; mt < 2; ++mt) {
            #pragma unroll
            for (int r = 0; r < 4; ++r) {
                int row = m0 + wm + mt * 16 + quad * 4 + r;
                if (row < M) {
                    #pragma unroll
                    for (int nt = 0; nt < 4; ++nt)
                        C[(size_t)row * N + n0 + wn + nt * 16 + mrow] = f2b(acc[mt][nt][r]);
                }
            }
        }
    }
}

extern "C" void kernel_launch(void* const* d_in, const int* in_sizes, int n_in,
                              void* d_out, int out_size, void* d_ws, size_t ws_size,
                              hipStream_t stream) {
    const float* x   = (const float*)d_in[0];
    const float* ew  = (const float*)d_in[1];
    const float* W1  = (const float*)d_in[2];
    const float* b1  = (const float*)d_in[3];
    const float* W2  = (const float*)d_in[4];
    const float* b2  = (const float*)d_in[5];
    const float* W3  = (const float*)d_in[6];
    const float* b3  = (const float*)d_in[7];
    const float* Wf1 = (const float*)d_in[8];
    const float* bf1 = (const float*)d_in[9];
    const float* Wf2 = (const float*)d_in[10];
    const float* bf2 = (const float*)d_in[11];
    const int* ei    = (const int*)d_in[12];
    const int* batch = (const int*)d_in[13];
    float* out = (float*)d_out;
    (void)in_sizes; (void)n_in; (void)out_size; (void)ws_size;

    char* p = (char*)d_ws;
    auto alloc = [&](size_t bytes) -> char* {
        char* r = p;
        p += (bytes + 255) & ~(size_t)255;
        return r;
    };
    u64*   deg_cnt = (u64*)alloc((size_t)NNODES * 8);
    float* dinv   = (float*)alloc((size_t)NNODES * 4);
    unsigned* edges = (unsigned*)alloc((size_t)NNODES * DCAP * 4);  // padded CSR, 12.8 MB
    int*   gp     = (int*)  alloc((size_t)NGRAPH * 512 * 4);
    unsigned short* f1   = (unsigned short*)alloc((size_t)NGRAPH * 1024 * 2);
    unsigned short* wt1  = (unsigned short*)alloc((size_t)128 * 128 * 2);
    unsigned short* wt2  = (unsigned short*)alloc((size_t)256 * 128 * 2);
    unsigned short* wt3  = (unsigned short*)alloc((size_t)512 * 256 * 2);
    unsigned short* wtf1 = (unsigned short*)alloc((size_t)1024 * 512 * 2);
    unsigned short* wtf2 = (unsigned short*)alloc((size_t)128 * 1024 * 2);
    unsigned short* bufA = (unsigned short*)alloc((size_t)NPAD * 256 * 2);
    unsigned short* bufB = (unsigned short*)alloc((size_t)NPAD * 256 * 2);
    unsigned short* P1   = bufB;   // layer-1 pre-GEMM result (consumed by agg1)
    // total ~68 MB

    const int MB128 = (NNODES + 127) / 128; // 391
    const int MB64  = (NNODES + 63) / 64;   // 782
    const int AGG = (NNODES + 3) / 4;       // 12500

    // preprocessing: memset + k_pre (edges + transposes) + P1 GEMM + k_prep
    hipMemsetAsync(deg_cnt, 0, (size_t)NNODES * 8, stream);
    k_pre<<<EBLK + TBLK, 256, 0, stream>>>(W1, W2, W3, Wf1, Wf2,
                                           wt1, wt2, wt3, wtf1, wtf2,
                                           (const int4*)ei, (const int4*)(ei + NEDGES),
                                           (const float4*)ew, deg_cnt, edges);
    // P1 = X @ W1 (raw, no bias/relu — applied in agg1's EPI)
    k_gemm_mfma<3, 1><<<dim3(1, MB64), 256, 0, stream>>>(x, wt1, nullptr, P1, NNODES, 128, 128);
    k_prep<<<1024, 256, 0, stream>>>(deg_cnt, dinv, gp);

    // layer 1: H1' = dinv * relu( A_hat @ P1 + b1 )
    k_aggregate<128, 1, true, true><<<AGG, 256, 0, stream>>>(P1, deg_cnt, edges, dinv, bufA, b1);
    // layer 2
    k_aggregate<128, 1, false, false><<<AGG, 256, 0, stream>>>(bufA, deg_cnt, edges, dinv, bufB, nullptr);
    k_gemm128<0><<<dim3(2, MB128), 256, 0, stream>>>(bufB, wt2, b2, bufA, nullptr, nullptr, dinv, NNODES, 256, 128);
    // layer 3 + fused pool (unscaled relu feeds the pool); feature-sliced aggregate (S=2)
    k_aggregate<256, 2, false, false><<<AGG * 2, 256, 0, stream>>>(bufA, deg_cnt, edges, dinv, bufB, nullptr);
    k_gemm128<2><<<dim3(4, MB128), 256, 0, stream>>>(bufB, wt3, b3, nullptr, batch, gp, nullptr, NNODES, 512, 256);

    // MLP head (legacy kernel, M=512)
    k_gemm_mfma<0, 1><<<dim3(8, NGRAPH / 64), 256, 0, stream>>>(gp, wtf1, bf1, f1, NGRAPH, 1024, 512);
    k_gemm_mfma<1, 0><<<dim3(1, NGRAPH / 64), 256, 0, stream>>>(f1, wtf2, bf2, out, NGRAPH, 128, 1024);
}

// Round 14
// 342.236 us; speedup vs baseline: 1.1015x; 1.0287x over previous
//
#include <hip/hip_runtime.h>

#define NNODES 50000
#define NPAD   50048   // 391 * 128; padded row count so 128-tile GEMM staging never faults
#define NEDGES 800000
#define NGRAPH 512
#define DCAP 64   // padded edge slots per node; Poisson(16) max ~37, P(>=64) ~ 1e-23

typedef short bf16x8 __attribute__((ext_vector_type(8)));
typedef unsigned short u16x8 __attribute__((ext_vector_type(8)));
typedef float f32x4 __attribute__((ext_vector_type(4)));
typedef unsigned long long u64;

// async global->LDS, 16B per lane (dest = wave-uniform base + lane*16, linear layout)
#define GLOAD16(g, l)                                                                 \
    __builtin_amdgcn_global_load_lds((const __attribute__((address_space(1))) unsigned*)(g), \
                                     (__attribute__((address_space(3))) unsigned*)(l), 16, 0, 0)

// ---------- bf16 <-> fp32 helpers ----------
static __device__ __forceinline__ float b2f(unsigned short u) {
    return __uint_as_float(((unsigned)u) << 16);
}
static __device__ __forceinline__ unsigned short f2b(float f) {
    unsigned u = __float_as_uint(f);
    unsigned r = (u + 0x7fffu + ((u >> 16) & 1u)) >> 16;  // round-nearest-even
    return (unsigned short)r;
}
static __device__ __forceinline__ float dinv_of(unsigned wsum_fixed) {
    return rsqrtf((float)wsum_fixed * 5.9604645e-8f + 1.0f);   // *2^-24, +1 self-loop
}

// accumulate 8 bf16 (packed in uint4) * c into acc[8]
static __device__ __forceinline__ void accum8(float (&acc)[8], float c, uint4 v) {
    unsigned w[4] = {v.x, v.y, v.z, v.w};
    #pragma unroll
    for (int i = 0; i < 4; ++i) {
        acc[2 * i]     += c * __uint_as_float(w[i] << 16);
        acc[2 * i + 1] += c * __uint_as_float(w[i] & 0xffff0000u);
    }
}

// ---------- fused preprocessing under the atomic wall (r10/r13-proven form) ----------
// Edge placement is memory-side atomic/scatter-store-bound (~56us, all pipes idle).
// LIGHT streaming work rides under it free (r10); heavy compute does not (r11/r12).
// Riding along: (a) all 5 weight transposes, (b) zeroing of gp / f1f32 / out.
#define EBLK 782   // ceil(200000/256) edge blocks (4 edges/thread)
#define TBLK 204   // transpose tiles: W1 4, W2 8, W3 32, Wf1 128, Wf2 32
#define ZBLK 832   // zero blocks: gp 256, f1f32 512, out 64 (uint4 stores)
__global__ __launch_bounds__(256) void k_pre(const float* __restrict__ W1, const float* __restrict__ W2,
                                             const float* __restrict__ W3, const float* __restrict__ Wf1,
                                             const float* __restrict__ Wf2,
                                             unsigned short* __restrict__ T1, unsigned short* __restrict__ T2,
                                             unsigned short* __restrict__ T3, unsigned short* __restrict__ Tf1,
                                             unsigned short* __restrict__ Tf2,
                                             const int4* __restrict__ ei_s, const int4* __restrict__ ei_d,
                                             const float4* __restrict__ ew4,
                                             u64* deg_cnt, unsigned* __restrict__ edges,
                                             int* __restrict__ gp, float* __restrict__ f1f32,
                                             float* __restrict__ outp) {
    __shared__ float sm[64][65];   // transpose branch only (16.6KB)
    const int b = blockIdx.x;
    const int tid = threadIdx.x;
    if (b < EBLK) {
        // edge placement: u64 atomic returns old count = this edge's slot; 4 chains/thread
        int t = b * 256 + tid;
        if (t >= NEDGES / 4) return;
        int4 ss = ei_s[t];
        int4 dd = ei_d[t];
        float4 ww = ew4[t];
        int s[4] = {ss.x, ss.y, ss.z, ss.w};
        int d[4] = {dd.x, dd.y, dd.z, dd.w};
        float w[4] = {ww.x, ww.y, ww.z, ww.w};
        int slot[4];
        #pragma unroll
        for (int u = 0; u < 4; ++u) {
            unsigned fixed = __float2uint_rn(w[u] * 16777216.0f);  // 8.24 fixed; ew in [0,1)
            u64 old = atomicAdd(&deg_cnt[d[u]], ((u64)1 << 32) | fixed);
            slot[u] = (int)(old >> 32);
            if (slot[u] > DCAP - 1) slot[u] = DCAP - 1;  // never fires (safety)
        }
        #pragma unroll
        for (int u = 0; u < 4; ++u)
            edges[((unsigned)d[u] << 6) | slot[u]] = ((unsigned)f2b(w[u]) << 16) | (unsigned)s[u];
        return;
    }
    if (b < EBLK + TBLK) {
        // ---- W[K][N] fp32 -> WT[N][K] bf16, 64x64 LDS tile, both sides coalesced ----
        const int bb = b - EBLK;
        const float* W; unsigned short* T; int K, N, t0;
        if (bb < 4)        { W = W1;  T = T1;  K = 128;  N = 128;  t0 = 0;   }
        else if (bb < 12)  { W = W2;  T = T2;  K = 128;  N = 256;  t0 = 4;   }
        else if (bb < 44)  { W = W3;  T = T3;  K = 256;  N = 512;  t0 = 12;  }
        else if (bb < 172) { W = Wf1; T = Tf1; K = 512;  N = 1024; t0 = 44;  }
        else               { W = Wf2; T = Tf2; K = 1024; N = 128;  t0 = 172; }
        const int tile = bb - t0;
        const int ntn = N >> 6;
        const int k0 = (tile / ntn) * 64, n0 = (tile % ntn) * 64;
        const int rr = tid >> 6, cc = tid & 63;
        #pragma unroll
        for (int r = 0; r < 16; ++r) {
            int kl = r * 4 + rr;
            sm[kl][cc] = W[(size_t)(k0 + kl) * N + n0 + cc];
        }
        __syncthreads();
        #pragma unroll
        for (int r = 0; r < 16; ++r) {
            int nl = r * 4 + rr;
            T[(size_t)(n0 + nl) * K + k0 + cc] = f2b(sm[cc][nl]);
        }
        return;
    }
    // ---- zero blocks: gp (1MB), f1f32 (2MB), out (256KB) — ride under the wall ----
    const int zb = b - EBLK - TBLK;
    if (zb >= ZBLK) return;
    const int idx = zb * 256 + tid;     // uint4 index
    uint4 z4 = {0u, 0u, 0u, 0u};
    if (zb < 256)       ((uint4*)gp)[idx] = z4;
    else if (zb < 768)  ((uint4*)f1f32)[idx - 65536] = z4;
    else                ((uint4*)outp)[idx - 196608] = z4;
}

// ---------- aggregation: Z[d,:] = epi( dinv[d] * (self + sum_e c_e * X[src_e,:]) ) ----------
// wave-per-(node, feature-slice). SLICES=2 (F=256): slice parity == XCD parity under
// round-robin dispatch -> 12.8MB half-table per XCD L2 (r8: FETCH 187->162MB).
// DSRC (agg1): X unscaled -> c_e = w_e * dinv[src], dinv computed INLINE from
// deg_cnt[src] lo-dword (k_prep eliminated); di inline from this node's deg_cnt;
// epilogue WRITES dinv[node] for downstream consumers (agg2/agg3/gemm2).
// EPI: fused layer-1 epilogue out = dinv * relu(z + bias).
// 16B dwordx4 gathers, rotating 2-deep pipeline, weight-0 masked tail,
// cross-group shfl reduce, 16B stores by group 0.
template <int F, int SLICES, bool DSRC, bool EPI>
__global__ __launch_bounds__(256) void k_aggregate(const unsigned short* __restrict__ X,
                                                   const u64* __restrict__ deg_cnt,
                                                   const unsigned* __restrict__ edges,
                                                   float* __restrict__ dinv,
                                                   unsigned short* __restrict__ Z,
                                                   const float* __restrict__ bias) {
    constexpr int FS = F / SLICES;     // features handled per block
    constexpr int LPR = FS / 8;        // lanes per source row-slice (16 or 32)
    constexpr int GRP = 64 / LPR;      // edges per step (4 or 2)
    constexpr int STEP = GRP * 2;      // edges per pair-iteration (8 or 4)
    const int bid = blockIdx.x;
    const int slice = (SLICES == 1) ? 0 : (bid & (SLICES - 1));
    const int chunk = (SLICES == 1) ? bid : (bid / SLICES);
    const int wave = threadIdx.x >> 6, lane = threadIdx.x & 63;
    const int node = chunk * 4 + wave;
    if (node >= NNODES) return;
    const int sub = lane & (LPR - 1);
    const int grp = lane / LPR;
    const int fo = slice * FS + sub * 8;
    const unsigned short* Xf = X + fo;
    const unsigned* deg_lo = (const unsigned*)deg_cnt;   // lo-dword view
    const u64 dc = deg_cnt[node];
    const int cnt = (int)(dc >> 32);
    const float di = DSRC ? dinv_of((unsigned)(dc & 0xffffffffull)) : dinv[node];
    const unsigned* erow = edges + ((unsigned)node << 6);

    // self row-slice: issue early, consumed in epilogue
    const uint4 selfv = *(const uint4*)(Xf + (size_t)node * F);

    float acc[8] = {};

    const int e0 = grp;
    const int nb = (cnt + STEP - 1) / STEP;   // pair-iterations (wave-uniform)

    unsigned pa0 = 0, pb0 = 0, pa1 = 0, pb1 = 0;
    uint4 va0 = {}, vb0 = {};
    float da0 = 1.f, db0 = 1.f;
    if (nb > 0) {
        int ea = e0, eb = e0 + GRP;
        pa0 = (ea < cnt) ? erow[ea] : 0u;
        pb0 = (eb < cnt) ? erow[eb] : 0u;
        va0 = *(const uint4*)(Xf + (size_t)(pa0 & 0xffffu) * F);
        vb0 = *(const uint4*)(Xf + (size_t)(pb0 & 0xffffu) * F);
        if constexpr (DSRC) {
            da0 = dinv_of(deg_lo[(pa0 & 0xffffu) << 1]);
            db0 = dinv_of(deg_lo[(pb0 & 0xffffu) << 1]);
        }
        if (nb > 1) {
            int ea1 = e0 + STEP, eb1 = ea1 + GRP;
            pa1 = (ea1 < cnt) ? erow[ea1] : 0u;
            pb1 = (eb1 < cnt) ? erow[eb1] : 0u;
        }
    }
    for (int p = 0; p < nb; ++p) {
        uint4 va1 = {}, vb1 = {};
        float da1 = 1.f, db1 = 1.f;
        unsigned pa2 = 0, pb2 = 0;
        if (p + 1 < nb) {
            va1 = *(const uint4*)(Xf + (size_t)(pa1 & 0xffffu) * F);
            vb1 = *(const uint4*)(Xf + (size_t)(pb1 & 0xffffu) * F);
            if constexpr (DSRC) {
                da1 = dinv_of(deg_lo[(pa1 & 0xffffu) << 1]);
                db1 = dinv_of(deg_lo[(pb1 & 0xffffu) << 1]);
            }
            if (p + 2 < nb) {
                int ea = e0 + (p + 2) * STEP, eb = ea + GRP;
                pa2 = (ea < cnt) ? erow[ea] : 0u;
                pb2 = (eb < cnt) ? erow[eb] : 0u;
            }
        }
        float ca = b2f((unsigned short)(pa0 >> 16));
        float cb = b2f((unsigned short)(pb0 >> 16));
        if constexpr (DSRC) { ca *= da0; cb *= db0; }
        accum8(acc, ca, va0);
        accum8(acc, cb, vb0);
        pa0 = pa1; pb0 = pb1; va0 = va1; vb0 = vb1;
        da0 = da1; db0 = db1;
        pa1 = pa2; pb1 = pb2;
    }

    // cross-group reduce
    #pragma unroll
    for (int j = 0; j < 8; ++j) {
        if constexpr (GRP == 4) acc[j] += __shfl_xor(acc[j], 16, 64);
        acc[j] += __shfl_xor(acc[j], 32, 64);
    }

    if (grp == 0) {
        if constexpr (DSRC) {
            if (sub == 0) dinv[node] = di;   // populate dinv for downstream kernels
        }
        float bv[8];
        if constexpr (EPI) {
            float4 q0 = *(const float4*)(bias + fo);
            float4 q1 = *(const float4*)(bias + fo + 4);
            bv[0] = q0.x; bv[1] = q0.y; bv[2] = q0.z; bv[3] = q0.w;
            bv[4] = q1.x; bv[5] = q1.y; bv[6] = q1.z; bv[7] = q1.w;
        }
        const float sc = DSRC ? di : 1.0f;   // self term scale (unscaled X path)
        unsigned w[4] = {selfv.x, selfv.y, selfv.z, selfv.w};
        unsigned o[4];
        #pragma unroll
        for (int i = 0; i < 4; ++i) {
            float s0 = __uint_as_float(w[i] << 16);
            float s1 = __uint_as_float(w[i] & 0xffff0000u);
            float z0 = di * (acc[2 * i] + sc * s0);
            float z1 = di * (acc[2 * i + 1] + sc * s1);
            if constexpr (EPI) {
                z0 = di * fmaxf(z0 + bv[2 * i], 0.f);
                z1 = di * fmaxf(z1 + bv[2 * i + 1], 0.f);
            }
            o[i] = (unsigned)f2b(z0) | ((unsigned)f2b(z1) << 16);
        }
        uint4 ov; ov.x = o[0]; ov.y = o[1]; ov.z = o[2]; ov.w = o[3];
        *(uint4*)(Z + (size_t)node * F + fo) = ov;
    }
}

// ---------- m97-structure GEMM, 2-phase double-buffered (T3-minimum) ----------
// 128x128 tile, 4 waves (2x2), each 64x64 = 4x4 16x16x32 fragments. BK=32.
// Double-buffered linear LDS [2][128][32]; next tile's global_load_lds issued BEFORE
// current tile's ds_read+MFMA; one vmcnt-drain barrier/tile. NPAD covers staging OOB.
// Bijective XCD chunking (m204). CMODE 0: bf16 store + relu + optional rscale.
// 2: fused per-graph relu+max-pool.
template <int CMODE>
__global__ __launch_bounds__(256) void k_gemm128(const unsigned short* __restrict__ A,
                                                 const unsigned short* __restrict__ WT,
                                                 const float* __restrict__ bias,
                                                 unsigned short* __restrict__ C,
                                                 const int* __restrict__ batch,
                                                 int* __restrict__ gp,
                                                 const float* __restrict__ rscale,
                                                 int M, int N, int K) {
    __shared__ unsigned short As[2][128 * 32];
    __shared__ unsigned short Bs[2][128 * 32];
    const int tid = threadIdx.x;

    // bijective XCD remap of flat block id (xcd = f % 8 under round-robin dispatch)
    const int nwg = gridDim.x * gridDim.y;
    const int f = blockIdx.y * gridDim.x + blockIdx.x;
    const int q = nwg >> 3, r = nwg & 7;
    const int xcd = f & 7, idx = f >> 3;
    const int w = (xcd < r) ? xcd * (q + 1) + idx : r * (q + 1) + (xcd - r) * q + idx;
    const int m0 = (w / gridDim.x) * 128;
    const int n0 = (w % gridDim.x) * 128;

    const int wave = tid >> 6, lane = tid & 63;
    const int wm = (wave >> 1) * 64, wn = (wave & 1) * 64;
    const int quad = lane >> 4, mrow = lane & 15;

    const int sr = tid >> 2;              // staging row 0..63
    const int sc = (tid & 3) * 8;         // staging col (shorts)
    const unsigned short* Ag0 = A + (size_t)(m0 + sr) * K + sc;
    const unsigned short* Ag1 = A + (size_t)(m0 + 64 + sr) * K + sc;
    const unsigned short* Bg0 = WT + (size_t)(n0 + sr) * K + sc;
    const unsigned short* Bg1 = WT + (size_t)(n0 + 64 + sr) * K + sc;
    const int so0 = sr * 32 + sc, so1 = (64 + sr) * 32 + sc;

    f32x4 acc[4][4] = {};
    const int nsteps = K >> 5;

    // prologue: stage tile 0 into buffer 0
    GLOAD16(Ag0, &As[0][so0]);
    GLOAD16(Ag1, &As[0][so1]);
    GLOAD16(Bg0, &Bs[0][so0]);
    GLOAD16(Bg1, &Bs[0][so1]);
    __syncthreads();   // vmcnt(0) drain + barrier

    for (int step = 0; step < nsteps; ++step) {
        const int cur = step & 1;
        if (step + 1 < nsteps) {           // issue next tile while computing current
            const int k1 = (step + 1) << 5;
            GLOAD16(Ag0 + k1, &As[cur ^ 1][so0]);
            GLOAD16(Ag1 + k1, &As[cur ^ 1][so1]);
            GLOAD16(Bg0 + k1, &Bs[cur ^ 1][so0]);
            GLOAD16(Bg1 + k1, &Bs[cur ^ 1][so1]);
        }
        bf16x8 af[4], bf[4];
        #pragma unroll
        for (int mt = 0; mt < 4; ++mt)
            af[mt] = *(const bf16x8*)&As[cur][(wm + mt * 16 + mrow) * 32 + quad * 8];
        #pragma unroll
        for (int nt = 0; nt < 4; ++nt)
            bf[nt] = *(const bf16x8*)&Bs[cur][(wn + nt * 16 + mrow) * 32 + quad * 8];
        #pragma unroll
        for (int mt = 0; mt < 4; ++mt)
            #pragma unroll
            for (int nt = 0; nt < 4; ++nt)
                acc[mt][nt] = __builtin_amdgcn_mfma_f32_16x16x32_bf16(af[mt], bf[nt], acc[mt][nt], 0, 0, 0);
        __syncthreads();   // drains prefetch vmcnt + this tile's lgkm; gates buffer reuse
    }

    float bn[4];
    #pragma unroll
    for (int nt = 0; nt < 4; ++nt) bn[nt] = bias[n0 + wn + nt * 16 + mrow];

    if constexpr (CMODE == 0) {
        #pragma unroll
        for (int mt = 0; mt < 4; ++mt) {
            #pragma unroll
            for (int r4 = 0; r4 < 4; ++r4) {
                int row = m0 + wm + mt * 16 + quad * 4 + r4;
                if (row < M) {
                    float rs = rscale ? rscale[row] : 1.0f;
                    #pragma unroll
                    for (int nt = 0; nt < 4; ++nt) {
                        float v = fmaxf(acc[mt][nt][r4] + bn[nt], 0.f) * rs;
                        C[(size_t)row * N + n0 + wn + nt * 16 + mrow] = f2b(v);
                    }
                }
            }
        }
    } else {
        // per-wave pool: wave covers 64 rows -> spans <=2 graphs (min graph size 97)
        const int wr0 = m0 + wm;
        int g0i = wr0 < M ? wr0 : M - 1;
        const int g0 = batch[g0i];
        int lastr = wr0 + 63; if (lastr >= M) lastr = M - 1;
        const int gl = batch[lastr];
        bool rok[16]; int gid[16];
        #pragma unroll
        for (int mt = 0; mt < 4; ++mt)
            #pragma unroll
            for (int r4 = 0; r4 < 4; ++r4) {
                int row = wr0 + mt * 16 + quad * 4 + r4;
                rok[mt * 4 + r4] = row < M;
                gid[mt * 4 + r4] = (row < M) ? batch[row] : -1;
            }
        #pragma unroll
        for (int nt = 0; nt < 4; ++nt) {
            float v0 = 0.f, v1 = 0.f;
            #pragma unroll
            for (int mt = 0; mt < 4; ++mt)
                #pragma unroll
                for (int r4 = 0; r4 < 4; ++r4)
                    if (rok[mt * 4 + r4]) {
                        float v = fmaxf(acc[mt][nt][r4] + bn[nt], 0.f);
                        if (gid[mt * 4 + r4] == g0) v0 = fmaxf(v0, v);
                        else v1 = fmaxf(v1, v);
                    }
            v0 = fmaxf(v0, __shfl_xor(v0, 16, 64));
            v0 = fmaxf(v0, __shfl_xor(v0, 32, 64));
            v1 = fmaxf(v1, __shfl_xor(v1, 16, 64));
            v1 = fmaxf(v1, __shfl_xor(v1, 32, 64));
            if (quad == 0) {
                int c = n0 + wn + nt * 16 + mrow;
                atomicMax(&gp[(size_t)g0 * N + c], __float_as_int(v0));
                if (gl != g0) atomicMax(&gp[(size_t)gl * N + c], __float_as_int(v1));
            }
        }
    }
}

// ---------- legacy GEMM: MLP head + P1 pre-GEMM, optional split-K ----------
// block 64(M) x 128(N), 4 waves (2x2 of 32x64), BK=32, 16x16x32 MFMA.
// Grid z = K-chunk (kchunk cols each). CMODE 0: bf16+relu. 1: fp32+bias. 3: raw bf16
// (no bias/relu). 4: split-K fp32 atomicAdd (dest zeroed; bias added by chunk 0).
// AFP: A is fp32. ARELU: relu applied to A on load (fp32 path).
template <int CMODE, int AFP, int ARELU>
__global__ __launch_bounds__(256) void k_gemm_mfma(const void* __restrict__ Av,
                                                   const unsigned short* __restrict__ WT,
                                                   const float* __restrict__ bias,
                                                   void* __restrict__ Cv,
                                                   int M, int N, int K, int kchunk) {
    constexpr int LDK = 40;
    __shared__ unsigned short As[64 * LDK];
    __shared__ unsigned short Bs[128 * LDK];
    const int tid = threadIdx.x;
    const int m0 = blockIdx.y * 64, n0 = blockIdx.x * 128;
    const int kb = blockIdx.z * kchunk, ke = kb + kchunk;
    const int wave = tid >> 6, lane = tid & 63;
    const int wm = (wave >> 1) * 32;
    const int wn = (wave & 1) * 64;
    const int quad = lane >> 4, mrow = lane & 15;

    const int ar = tid >> 2;
    const int ak = (tid & 3) * 8;
    const bool arow_ok = (m0 + ar) < M;
    const size_t aoff = (size_t)(m0 + ar) * K + ak;
    const unsigned short* Bg0 = WT + (size_t)(n0 + ar) * K + ak;
    const unsigned short* Bg1 = WT + (size_t)(n0 + ar + 64) * K + ak;

    f32x4 acc[2][4] = {};

    for (int k0 = kb; k0 < ke; k0 += 32) {
        u16x8 av = {};
        if (arow_ok) {
            if constexpr (AFP) {
                const float* Af = (const float*)Av + aoff + k0;
                float4 f0 = *(const float4*)Af;
                float4 f1 = *(const float4*)(Af + 4);
                if constexpr (ARELU) {
                    f0.x = fmaxf(f0.x, 0.f); f0.y = fmaxf(f0.y, 0.f);
                    f0.z = fmaxf(f0.z, 0.f); f0.w = fmaxf(f0.w, 0.f);
                    f1.x = fmaxf(f1.x, 0.f); f1.y = fmaxf(f1.y, 0.f);
                    f1.z = fmaxf(f1.z, 0.f); f1.w = fmaxf(f1.w, 0.f);
                }
                av[0] = (short)f2b(f0.x); av[1] = (short)f2b(f0.y);
                av[2] = (short)f2b(f0.z); av[3] = (short)f2b(f0.w);
                av[4] = (short)f2b(f1.x); av[5] = (short)f2b(f1.y);
                av[6] = (short)f2b(f1.z); av[7] = (short)f2b(f1.w);
            } else {
                av = *(const u16x8*)((const unsigned short*)Av + aoff + k0);
            }
        }
        u16x8 bv0 = *(const u16x8*)(Bg0 + k0);
        u16x8 bv1 = *(const u16x8*)(Bg1 + k0);
        *(u16x8*)&As[ar * LDK + ak] = av;
        *(u16x8*)&Bs[ar * LDK + ak] = bv0;
        *(u16x8*)&Bs[(ar + 64) * LDK + ak] = bv1;
        __syncthreads();
        bf16x8 af[2], bf[4];
        #pragma unroll
        for (int mt = 0; mt < 2; ++mt)
            af[mt] = *(const bf16x8*)&As[(wm + mt * 16 + mrow) * LDK + quad * 8];
        #pragma unroll
        for (int nt = 0; nt < 4; ++nt)
            bf[nt] = *(const bf16x8*)&Bs[(wn + nt * 16 + mrow) * LDK + quad * 8];
        #pragma unroll
        for (int mt = 0; mt < 2; ++mt)
            #pragma unroll
            for (int nt = 0; nt < 4; ++nt)
                acc[mt][nt] = __builtin_amdgcn_mfma_f32_16x16x32_bf16(af[mt], bf[nt], acc[mt][nt], 0, 0, 0);
        __syncthreads();
    }

    float bn[4] = {0.f, 0.f, 0.f, 0.f};
    if constexpr (CMODE != 3) {
        #pragma unroll
        for (int nt = 0; nt < 4; ++nt) bn[nt] = bias[n0 + wn + nt * 16 + mrow];
    }

    if constexpr (CMODE == 0) {
        unsigned short* C = (unsigned short*)Cv;
        #pragma unroll
        for (int mt = 0; mt < 2; ++mt) {
            #pragma unroll
            for (int r = 0; r < 4; ++r) {
                int row = m0 + wm + mt * 16 + quad * 4 + r;
                if (row < M) {
                    #pragma unroll
                    for (int nt = 0; nt < 4; ++nt) {
                        float v = fmaxf(acc[mt][nt][r] + bn[nt], 0.f);
                        C[(size_t)row * N + n0 + wn + nt * 16 + mrow] = f2b(v);
                    }
                }
            }
        }
    } else if constexpr (CMODE == 1) {
        float* C = (float*)Cv;
        #pragma unroll
        for (int mt = 0; mt < 2; ++mt) {
            #pragma unroll
            for (int r = 0; r < 4; ++r) {
                int row = m0 + wm + mt * 16 + quad * 4 + r;
                if (row < M) {
                    #pragma unroll
                    for (int nt = 0; nt < 4; ++nt)
                        C[(size_t)row * N + n0 + wn + nt * 16 + mrow] = acc[mt][nt][r] + bn[nt];
                }
            }
        }
    } else if constexpr (CMODE == 3) {
        unsigned short* C = (unsigned short*)Cv;
        #pragma unroll
        for (int mt = 0; mt < 2; ++mt) {
            #pragma unroll
            for (int r = 0; r < 4; ++r) {
                int row = m0 + wm + mt * 16 + quad * 4 + r;
                if (row < M) {
                    #pragma unroll
                    for (int nt = 0; nt < 4; ++nt)
                        C[(size_t)row * N + n0 + wn + nt * 16 + mrow] = f2b(acc[mt][nt][r]);
                }
            }
        }
    } else {
        // split-K: fp32 atomic accumulate (dest zeroed in k_pre); chunk 0 adds bias
        float* C = (float*)Cv;
        const bool addb = (kb == 0);
        #pragma unroll
        for (int mt = 0; mt < 2; ++mt) {
            #pragma unroll
            for (int r = 0; r < 4; ++r) {
                int row = m0 + wm + mt * 16 + quad * 4 + r;
                if (row < M) {
                    #pragma unroll
                    for (int nt = 0; nt < 4; ++nt) {
                        float v = acc[mt][nt][r] + (addb ? bn[nt] : 0.f);
                        atomicAdd(&C[(size_t)row * N + n0 + wn + nt * 16 + mrow], v);
                    }
                }
            }
        }
    }
}

extern "C" void kernel_launch(void* const* d_in, const int* in_sizes, int n_in,
                              void* d_out, int out_size, void* d_ws, size_t ws_size,
                              hipStream_t stream) {
    const float* x   = (const float*)d_in[0];
    const float* ew  = (const float*)d_in[1];
    const float* W1  = (const float*)d_in[2];
    const float* b1  = (const float*)d_in[3];
    const float* W2  = (const float*)d_in[4];
    const float* b2  = (const float*)d_in[5];
    const float* W3  = (const float*)d_in[6];
    const float* b3  = (const float*)d_in[7];
    const float* Wf1 = (const float*)d_in[8];
    const float* bf1 = (const float*)d_in[9];
    const float* Wf2 = (const float*)d_in[10];
    const float* bf2 = (const float*)d_in[11];
    const int* ei    = (const int*)d_in[12];
    const int* batch = (const int*)d_in[13];
    float* out = (float*)d_out;
    (void)in_sizes; (void)n_in; (void)out_size; (void)ws_size;

    char* p = (char*)d_ws;
    auto alloc = [&](size_t bytes) -> char* {
        char* r = p;
        p += (bytes + 255) & ~(size_t)255;
        return r;
    };
    u64*   deg_cnt = (u64*)alloc((size_t)NNODES * 8);
    float* dinv   = (float*)alloc((size_t)NNODES * 4);
    unsigned* edges = (unsigned*)alloc((size_t)NNODES * DCAP * 4);  // padded CSR, 12.8 MB
    int*   gp     = (int*)  alloc((size_t)NGRAPH * 512 * 4);
    float* f1f32  = (float*)alloc((size_t)NGRAPH * 1024 * 4);      // fp32 split-K accum
    unsigned short* wt1  = (unsigned short*)alloc((size_t)128 * 128 * 2);
    unsigned short* wt2  = (unsigned short*)alloc((size_t)256 * 128 * 2);
    unsigned short* wt3  = (unsigned short*)alloc((size_t)512 * 256 * 2);
    unsigned short* wtf1 = (unsigned short*)alloc((size_t)1024 * 512 * 2);
    unsigned short* wtf2 = (unsigned short*)alloc((size_t)128 * 1024 * 2);
    unsigned short* bufA = (unsigned short*)alloc((size_t)NPAD * 256 * 2);
    unsigned short* bufB = (unsigned short*)alloc((size_t)NPAD * 256 * 2);
    unsigned short* P1   = bufB;   // layer-1 pre-GEMM result (consumed by agg1)
    // total ~69 MB

    const int MB128 = (NNODES + 127) / 128; // 391
    const int MB64  = (NNODES + 63) / 64;   // 782
    const int AGG = (NNODES + 3) / 4;       // 12500

    // preprocessing: memset + k_pre (edges + transposes + zeros) + P1 GEMM
    hipMemsetAsync(deg_cnt, 0, (size_t)NNODES * 8, stream);
    k_pre<<<EBLK + TBLK + ZBLK, 256, 0, stream>>>(W1, W2, W3, Wf1, Wf2,
                                                  wt1, wt2, wt3, wtf1, wtf2,
                                                  (const int4*)ei, (const int4*)(ei + NEDGES),
                                                  (const float4*)ew, deg_cnt, edges,
                                                  gp, f1f32, out);
    // P1 = X @ W1 (raw; bias+relu applied in agg1's EPI)
    k_gemm_mfma<3, 1, 0><<<dim3(1, MB64), 256, 0, stream>>>(x, wt1, nullptr, P1, NNODES, 128, 128, 128);

    // layer 1: H1' = dinv * relu( A_hat @ P1 + b1 ); also populates dinv[] inline
    k_aggregate<128, 1, true, true><<<AGG, 256, 0, stream>>>(P1, deg_cnt, edges, dinv, bufA, b1);
    // layer 2
    k_aggregate<128, 1, false, false><<<AGG, 256, 0, stream>>>(bufA, deg_cnt, edges, dinv, bufB, nullptr);
    k_gemm128<0><<<dim3(2, MB128), 256, 0, stream>>>(bufB, wt2, b2, bufA, nullptr, nullptr, dinv, NNODES, 256, 128);
    // layer 3 + fused pool (unscaled relu feeds the pool); feature-sliced aggregate (S=2)
    k_aggregate<256, 2, false, false><<<AGG * 2, 256, 0, stream>>>(bufA, deg_cnt, edges, dinv, bufB, nullptr);
    k_gemm128<2><<<dim3(4, MB128), 256, 0, stream>>>(bufB, wt3, b3, nullptr, batch, gp, nullptr, NNODES, 512, 256);

    // MLP head: f1f32 = gp@Wf1 + bf1 (split-K x2, fp32 accum, no relu);
    // out = relu(f1f32)@Wf2 + bf2 (split-K x4, relu fused into A-load)
    k_gemm_mfma<4, 1, 0><<<dim3(8, NGRAPH / 64, 2), 256, 0, stream>>>(gp, wtf1, bf1, f1f32, NGRAPH, 1024, 512, 256);
    k_gemm_mfma<4, 1, 1><<<dim3(1, NGRAPH / 64, 4), 256, 0, stream>>>(f1f32, wtf2, bf2, out, NGRAPH, 128, 1024, 256);
}